// Round 4
// baseline (508.290 us; speedup 1.0000x reference)
//
#include <hip/hip_runtime.h>
#include <stdint.h>

#define D_MODEL 1024
#define NHEAD   16
#define HDIM    64
#define FFDIM   4096
#define BATCH   4
#define SEQ     2048
#define ROWS    (BATCH*SEQ)   // 8192

typedef unsigned short u16;
typedef __bf16 bf16_t;
typedef bf16_t bf16x8 __attribute__((ext_vector_type(8)));
typedef float  f32x4  __attribute__((ext_vector_type(4)));

__device__ __forceinline__ u16 f2bf(float f) {
  union { float f; unsigned u; } v; v.f = f;
  unsigned r = v.u + 0x7fffu + ((v.u >> 16) & 1u);
  return (u16)(r >> 16);
}

__device__ __forceinline__ void gl2lds16(const void* g, void* l) {
  __builtin_amdgcn_global_load_lds((const __attribute__((address_space(1))) void*)g,
                                   (__attribute__((address_space(3))) void*)l, 16, 0, 0);
}

#define MFMA_BF16(a, b, c) __builtin_amdgcn_mfma_f32_16x16x32_bf16((a), (b), (c), 0, 0, 0)
#define EXP2(x) __builtin_amdgcn_exp2f(x)

// ---------------- LayerNorm (fp32 in -> bf16 out) ----------------
__global__ __launch_bounds__(256) void ln_kernel(const float* __restrict__ x,
                                                 const float* __restrict__ g,
                                                 const float* __restrict__ be,
                                                 u16* __restrict__ out) {
  __shared__ float red[10];
  int row = blockIdx.x;
  int t = threadIdx.x;
  const float* xr = x + (size_t)row * D_MODEL;
  float4 xv = ((const float4*)xr)[t];
  float s  = xv.x + xv.y + xv.z + xv.w;
  float s2 = xv.x*xv.x + xv.y*xv.y + xv.z*xv.z + xv.w*xv.w;
  for (int d = 32; d > 0; d >>= 1) { s += __shfl_down(s, d); s2 += __shfl_down(s2, d); }
  int wid = t >> 6;
  if ((t & 63) == 0) { red[wid*2] = s; red[wid*2+1] = s2; }
  __syncthreads();
  if (t == 0) {
    float a = 0.f, b2 = 0.f;
    for (int i = 0; i < 4; ++i) { a += red[i*2]; b2 += red[i*2+1]; }
    red[8] = a; red[9] = b2;
  }
  __syncthreads();
  float mu  = red[8] * (1.0f / D_MODEL);
  float var = red[9] * (1.0f / D_MODEL) - mu*mu;
  float rstd = rsqrtf(var + 1e-12f);
  float4 gv = ((const float4*)g)[t];
  float4 bv = ((const float4*)be)[t];
  unsigned long long o =
      (unsigned long long)f2bf((xv.x - mu) * rstd * gv.x + bv.x)
    | ((unsigned long long)f2bf((xv.y - mu) * rstd * gv.y + bv.y) << 16)
    | ((unsigned long long)f2bf((xv.z - mu) * rstd * gv.z + bv.z) << 32)
    | ((unsigned long long)f2bf((xv.w - mu) * rstd * gv.w + bv.w) << 48);
  ((unsigned long long*)out)[(size_t)row * (D_MODEL/4) + t] = o;
}

// ---------------- Weight transpose fp32 [K,N] -> bf16 [N,K] ----------------
__global__ __launch_bounds__(256) void wt_kernel(const float* __restrict__ W,
                                                 u16* __restrict__ Wt, int K, int N) {
  __shared__ float tile[32][33];
  int n0 = blockIdx.x * 32, k0 = blockIdx.y * 32;
  int tx = threadIdx.x & 31, ty = threadIdx.x >> 5;   // ty: 0..7
  #pragma unroll
  for (int i = 0; i < 4; ++i) {
    int k = ty + i*8;
    tile[k][tx] = W[(size_t)(k0 + k) * N + n0 + tx];
  }
  __syncthreads();
  #pragma unroll
  for (int i = 0; i < 4; ++i) {
    int n = ty + i*8;
    Wt[(size_t)(n0 + n) * K + k0 + tx] = f2bf(tile[tx][n]);
  }
}

// ---------------- V transpose: [b,key,h,d] bf16 -> [b,h,d,key] bf16 --------
__global__ __launch_bounds__(256) void vtrans_kernel(const u16* __restrict__ vb,
                                                     u16* __restrict__ vt) {
  __shared__ __align__(16) u16 tile[64][80];
  int kb = blockIdx.x * 64;       // key block
  int bh = blockIdx.y;            // b*16+h
  int b = bh >> 4, h = bh & 15;
  int t = threadIdx.x;
  int key = t >> 2, dq = (t & 3) * 16;
  const u16* src = vb + (size_t)b*SEQ*D_MODEL + (size_t)(kb+key)*D_MODEL + h*HDIM + dq;
  *(bf16x8*)&tile[key][dq]     = *(const bf16x8*)(src);
  *(bf16x8*)&tile[key][dq + 8] = *(const bf16x8*)(src + 8);
  __syncthreads();
  int w = t >> 6, lane = t & 63;
  int kq = w * 16;
  u16 vals[16];
  #pragma unroll
  for (int e = 0; e < 16; ++e) vals[e] = tile[kq + e][lane];
  u16* dst = vt + (size_t)bh * HDIM * SEQ + (size_t)lane * SEQ + kb + kq;
  *(bf16x8*)dst       = *(const bf16x8*)&vals[0];
  *(bf16x8*)(dst + 8) = *(const bf16x8*)&vals[8];
}

// ---------------- GEMM 128x256, BK=64, tri-buffered, counted vmcnt ---------
// EPI 0: bf16 out = C + bias
// EPI 1: f32  out = resid + C + bias
// EPI 2: bf16 out = gelu(C + bias)
// EPI 3: QKV fused: N=3072; route by section bn>>2 to outp/out2/out3 with
//        bias/bias2/bias3; output stride 1024 each.
__device__ __forceinline__ float gelu_f(float v) {
  return 0.5f * v * (1.0f + erff(v * 0.70710678118654752f));
}

template<int EPI>
__global__ __launch_bounds__(512, 2) void gemm256(const u16* __restrict__ A,
                                                  const u16* __restrict__ Bt,
                                                  const float* __restrict__ bias,
                                                  const float* __restrict__ resid,
                                                  void* __restrict__ outp,
                                                  int M, int N, int K,
                                                  const float* __restrict__ bias2,
                                                  const float* __restrict__ bias3,
                                                  void* __restrict__ out2,
                                                  void* __restrict__ out3) {
  __shared__ __align__(16) u16 sA[3][128*64];   // 48 KiB
  __shared__ __align__(16) u16 sB[3][256*64];   // 96 KiB
  const int tid = threadIdx.x;
  const int lane = tid & 63, w = tid >> 6;
  const int r = lane & 15, kg = lane >> 4, r7 = r & 7;
  const int wr = w >> 2, wc = w & 3;

  // XCD-aware bijective swizzle (all launches have nwg % 8 == 0)
  const int gx = gridDim.x;
  const int nwg = gx * gridDim.y;
  const int orig = blockIdx.y * gx + blockIdx.x;
  const int lid = (orig & 7) * (nwg >> 3) + (orig >> 3);
  const int bm = lid / gx, bn = lid % gx;

  const int NT = K >> 6;

  size_t offA[2], offB[4];
  #pragma unroll
  for (int u = 0; u < 2; ++u) {
    int slot = u*512 + tid;
    int row = slot >> 3, g = slot & 7;
    offA[u] = (size_t)(bm*128 + row) * K + ((g ^ (row & 7)) * 8);
  }
  #pragma unroll
  for (int u = 0; u < 4; ++u) {
    int slot = u*512 + tid;
    int row = slot >> 3, g = slot & 7;
    offB[u] = (size_t)(bn*256 + row) * K + ((g ^ (row & 7)) * 8);
  }

  f32x4 acc[4][4];
  #pragma unroll
  for (int m = 0; m < 4; ++m)
    #pragma unroll
    for (int n = 0; n < 4; ++n) acc[m][n] = f32x4{0.f, 0.f, 0.f, 0.f};

  // per-section routing for EPI 3 (wave-uniform: bn 0-3 q, 4-7 k, 8-11 v)
  const float* bsel = bias;
  u16* osel = (u16*)outp;
  int bnl = bn;
  if (EPI == 3) {
    int sec = bn >> 2;
    bsel = (sec == 0) ? bias : (sec == 1 ? bias2 : bias3);
    osel = (u16*)((sec == 0) ? outp : (sec == 1 ? out2 : out3));
    bnl = bn & 3;
  }
  float bv4[4];
  #pragma unroll
  for (int n = 0; n < 4; ++n) bv4[n] = bsel[bnl*256 + wc*64 + n*16 + r];

  // ---- prologue: stage K-tiles 0 and 1 ----
  #pragma unroll
  for (int u = 0; u < 2; ++u) gl2lds16(A  + offA[u],      &sA[0][(u*512+tid)*8]);
  #pragma unroll
  for (int u = 0; u < 4; ++u) gl2lds16(Bt + offB[u],      &sB[0][(u*512+tid)*8]);
  #pragma unroll
  for (int u = 0; u < 2; ++u) gl2lds16(A  + offA[u] + 64, &sA[1][(u*512+tid)*8]);
  #pragma unroll
  for (int u = 0; u < 4; ++u) gl2lds16(Bt + offB[u] + 64, &sB[1][(u*512+tid)*8]);
  asm volatile("s_waitcnt vmcnt(6)" ::: "memory");
  __builtin_amdgcn_s_barrier();

  int buf = 0;
  for (int t = 0; t < NT; ++t) {
    const bool pre = (t + 2 < NT);
    int nb = buf + 2; if (nb >= 3) nb -= 3;
    const size_t koff = (size_t)(t + 2) * 64;

    // ======== phase 0 (k-slice 0) ========
    bf16x8 af0[4], bf0[4];
    #pragma unroll
    for (int m = 0; m < 4; ++m)
      af0[m] = *(const bf16x8*)&sA[buf][(wr*64 + m*16 + r)*64 + ((kg ^ r7) * 8)];
    #pragma unroll
    for (int n = 0; n < 4; ++n)
      bf0[n] = *(const bf16x8*)&sB[buf][(wc*64 + n*16 + r)*64 + ((kg ^ r7) * 8)];
    if (pre) {
      gl2lds16(A  + offA[0] + koff, &sA[nb][(0*512+tid)*8]);
      gl2lds16(A  + offA[1] + koff, &sA[nb][(1*512+tid)*8]);
      gl2lds16(Bt + offB[0] + koff, &sB[nb][(0*512+tid)*8]);
    }
    __builtin_amdgcn_s_barrier();
    asm volatile("s_waitcnt lgkmcnt(0)" ::: "memory");
    __builtin_amdgcn_s_setprio(1);
    #pragma unroll
    for (int m = 0; m < 4; ++m)
      #pragma unroll
      for (int n = 0; n < 4; ++n)
        acc[m][n] = MFMA_BF16(af0[m], bf0[n], acc[m][n]);
    __builtin_amdgcn_s_setprio(0);
    __builtin_amdgcn_s_barrier();

    // ======== phase 1 (k-slice 1) ========
    bf16x8 af1[4], bf1[4];
    #pragma unroll
    for (int m = 0; m < 4; ++m)
      af1[m] = *(const bf16x8*)&sA[buf][(wr*64 + m*16 + r)*64 + (((4 + kg) ^ r7) * 8)];
    #pragma unroll
    for (int n = 0; n < 4; ++n)
      bf1[n] = *(const bf16x8*)&sB[buf][(wc*64 + n*16 + r)*64 + (((4 + kg) ^ r7) * 8)];
    if (pre) {
      gl2lds16(Bt + offB[1] + koff, &sB[nb][(1*512+tid)*8]);
      gl2lds16(Bt + offB[2] + koff, &sB[nb][(2*512+tid)*8]);
      gl2lds16(Bt + offB[3] + koff, &sB[nb][(3*512+tid)*8]);
    }
    __builtin_amdgcn_s_barrier();
    asm volatile("s_waitcnt lgkmcnt(0)" ::: "memory");
    __builtin_amdgcn_s_setprio(1);
    #pragma unroll
    for (int m = 0; m < 4; ++m)
      #pragma unroll
      for (int n = 0; n < 4; ++n)
        acc[m][n] = MFMA_BF16(af1[m], bf1[n], acc[m][n]);
    __builtin_amdgcn_s_setprio(0);
    if (pre) asm volatile("s_waitcnt vmcnt(6)" ::: "memory");
    else     asm volatile("s_waitcnt vmcnt(0)" ::: "memory");
    __builtin_amdgcn_s_barrier();
    buf += 1; if (buf >= 3) buf -= 3;
  }

  // ---- epilogue ----
  const int orow = bm*128 + wr*64;
  const int ocol = (EPI == 3 ? bnl : bn)*256 + wc*64;
  const int ostride = (EPI == 3) ? 1024 : N;
  #pragma unroll
  for (int m = 0; m < 4; ++m) {
    #pragma unroll
    for (int n = 0; n < 4; ++n) {
      #pragma unroll
      for (int j = 0; j < 4; ++j) {
        int rr = orow + m*16 + kg*4 + j;
        int cc = ocol + n*16 + r;
        size_t idx = (size_t)rr * ostride + cc;
        float v = acc[m][n][j] + bv4[n];
        if (EPI == 0)       ((u16*)outp)[idx]   = f2bf(v);
        else if (EPI == 1)  ((float*)outp)[idx] = resid[idx] + v;
        else if (EPI == 2)  ((u16*)outp)[idx]   = f2bf(gelu_f(v));
        else                osel[idx]           = f2bf(v);
      }
    }
  }
}

// ---------------- Flash attention: 4 waves/block, QBLK=32/wave, KVBLK=64 ---
__global__ __launch_bounds__(256, 3) void attn_kernel(const u16* __restrict__ qb,
                                                      const u16* __restrict__ kb,
                                                      const u16* __restrict__ vt,
                                                      const int* __restrict__ mask,
                                                      u16* __restrict__ ob) {
  __shared__ __align__(16) u16 sK[2][64*64];
  __shared__ __align__(16) u16 sV[2][64*64];
  __shared__ __align__(16) bf16_t sP[4][32*64];
  const float SC   = 0.18033688011112042f;   // 0.125 * log2(e)
  const float THR2 = 11.541560327111708f;    // 8 * log2(e)
  int tid = threadIdx.x;
  int lane = tid & 63, w = tid >> 6;
  int r = lane & 15, kg = lane >> 4;
  int r7 = r & 7;
  int qt = blockIdx.x;            // 0..15 (128 q-rows per block)
  int bh = blockIdx.y;
  int b = bh >> 4, h = bh & 15;
  size_t qkbase = (size_t)b * SEQ * D_MODEL + (size_t)h * HDIM;
  const u16* vtb = vt + (size_t)bh * HDIM * SEQ;
  const int* mrow = mask + b * SEQ;

  // Q fragments: rows qt*128 + w*32 + mq*16 + r
  const u16* qrow = qb + qkbase + (size_t)(qt*128 + w*32 + r) * D_MODEL + kg*8;
  bf16x8 qf[2][2];
  qf[0][0] = *(const bf16x8*)(qrow);
  qf[0][1] = *(const bf16x8*)(qrow + 32);
  qf[1][0] = *(const bf16x8*)(qrow + 16*D_MODEL);
  qf[1][1] = *(const bf16x8*)(qrow + 16*D_MODEL + 32);

  f32x4 oacc[2][4];
  #pragma unroll
  for (int mq = 0; mq < 2; ++mq)
    #pragma unroll
    for (int n = 0; n < 4; ++n) oacc[mq][n] = f32x4{0.f, 0.f, 0.f, 0.f};
  float m_run[2][4], lsum[2][4];
  #pragma unroll
  for (int mq = 0; mq < 2; ++mq)
    #pragma unroll
    for (int j = 0; j < 4; ++j) { m_run[mq][j] = -1e30f; lsum[mq][j] = 0.f; }

  // staging pointers (strength-reduced): chunk c0 = w*64+lane, c1 = +256
  int ch0 = w*64 + lane, ch1 = ch0 + 256;
  int row0 = ch0 >> 3, col0 = ((ch0 & 7) ^ (row0 & 7)) * 8;
  int row1 = ch1 >> 3, col1 = ((ch1 & 7) ^ (row1 & 7)) * 8;
  const u16* kp0 = kb + qkbase + (size_t)row0 * D_MODEL + col0;
  const u16* kp1 = kb + qkbase + (size_t)row1 * D_MODEL + col1;
  const u16* vp0 = vtb + (size_t)row0 * SEQ + col0;
  const u16* vp1 = vtb + (size_t)row1 * SEQ + col1;

  const int NT = SEQ / 64;

  // prologue stage tile 0
  gl2lds16(kp0, &sK[0][ch0*8]);
  gl2lds16(kp1, &sK[0][ch1*8]);
  gl2lds16(vp0, &sV[0][ch0*8]);
  gl2lds16(vp1, &sV[0][ch1*8]);
  kp0 += 64*D_MODEL; kp1 += 64*D_MODEL; vp0 += 64; vp1 += 64;

  #pragma unroll 2
  for (int kt = 0; kt < NT; ++kt) {
    int cur = kt & 1;
    int key0 = kt * 64;
    if (kt + 1 < NT) {
      gl2lds16(kp0, &sK[cur^1][ch0*8]);
      gl2lds16(kp1, &sK[cur^1][ch1*8]);
      gl2lds16(vp0, &sV[cur^1][ch0*8]);
      gl2lds16(vp1, &sV[cur^1][ch1*8]);
      kp0 += 64*D_MODEL; kp1 += 64*D_MODEL; vp0 += 64; vp1 += 64;
      asm volatile("s_waitcnt vmcnt(4)" ::: "memory");
    } else {
      asm volatile("s_waitcnt vmcnt(0)" ::: "memory");
    }
    __builtin_amdgcn_s_barrier();

    const u16* Kt = sK[cur];
    const u16* Vt = sV[cur];

    // ---- QK^T: 32q x 64k; kf reused across the two q-row blocks ----
    f32x4 s[2][4];
    #pragma unroll
    for (int mq = 0; mq < 2; ++mq)
      #pragma unroll
      for (int n = 0; n < 4; ++n) s[mq][n] = f32x4{0.f, 0.f, 0.f, 0.f};
    #pragma unroll
    for (int c = 0; c < 2; ++c) {
      #pragma unroll
      for (int n = 0; n < 4; ++n) {
        bf16x8 kf = *(const bf16x8*)&Kt[(n*16 + r)*64 + (((c*4 + kg) ^ r7) * 8)];
        s[0][n] = MFMA_BF16(qf[0][c], kf, s[0][n]);
        s[1][n] = MFMA_BF16(qf[1][c], kf, s[1][n]);
      }
    }

    // ---- mask + scale (exp2 domain); lane-local max ----
    int mk[4];
    #pragma unroll
    for (int n = 0; n < 4; ++n) mk[n] = mrow[key0 + n*16 + r];
    float tm[2][4];
    #pragma unroll
    for (int mq = 0; mq < 2; ++mq) {
      #pragma unroll
      for (int n = 0; n < 4; ++n) {
        #pragma unroll
        for (int j = 0; j < 4; ++j) {
          float v = mk[n] ? s[mq][n][j] * SC : -1e9f;
          s[mq][n][j] = v;
          tm[mq][j] = (n == 0) ? v : fmaxf(tm[mq][j], v);
        }
      }
    }
    // ---- defer-max rescale (rare) ----
    bool grow = false;
    #pragma unroll
    for (int mq = 0; mq < 2; ++mq)
      #pragma unroll
      for (int j = 0; j < 4; ++j) grow |= (tm[mq][j] > m_run[mq][j] + THR2);
    if (__any(grow)) {
      #pragma unroll
      for (int d = 1; d < 16; d <<= 1) {
        #pragma unroll
        for (int mq = 0; mq < 2; ++mq)
          #pragma unroll
          for (int j = 0; j < 4; ++j) tm[mq][j] = fmaxf(tm[mq][j], __shfl_xor(tm[mq][j], d));
      }
      #pragma unroll
      for (int mq = 0; mq < 2; ++mq) {
        #pragma unroll
        for (int j = 0; j < 4; ++j) {
          float mn = fmaxf(m_run[mq][j], tm[mq][j]);
          float al = EXP2(m_run[mq][j] - mn);
          m_run[mq][j] = mn;
          lsum[mq][j] *= al;
          oacc[mq][0][j] *= al; oacc[mq][1][j] *= al;
          oacc[mq][2][j] *= al; oacc[mq][3][j] *= al;
        }
      }
    }
    // ---- P = exp2(s - m); lane-local row-sum; per-wave LDS (swizzled) ----
    bf16_t* pw = sP[w];
    #pragma unroll
    for (int mq = 0; mq < 2; ++mq) {
      #pragma unroll
      for (int n = 0; n < 4; ++n) {
        int cg = n*2 + (r >> 3);
        #pragma unroll
        for (int j = 0; j < 4; ++j) {
          float p = EXP2(s[mq][n][j] - m_run[mq][j]);
          lsum[mq][j] += p;
          int rowp = mq*16 + kg*4 + j;
          pw[rowp*64 + ((cg ^ (rowp & 7)) * 8) + r7] = (bf16_t)p;
        }
      }
    }
    bf16x8 pa[2][2];
    #pragma unroll
    for (int mq = 0; mq < 2; ++mq)
      #pragma unroll
      for (int c = 0; c < 2; ++c)
        pa[mq][c] = *(const bf16x8*)&sP[w][(mq*16 + r)*64 + (((c*4 + kg) ^ r7) * 8)];
    #pragma unroll
    for (int n = 0; n < 4; ++n) {
      #pragma unroll
      for (int c = 0; c < 2; ++c) {
        bf16x8 vf = *(const bf16x8*)&Vt[(n*16 + r)*64 + (((c*4 + kg) ^ r7) * 8)];
        oacc[0][n] = MFMA_BF16(pa[0][c], vf, oacc[0][n]);
        oacc[1][n] = MFMA_BF16(pa[1][c], vf, oacc[1][n]);
      }
    }
    __builtin_amdgcn_s_barrier();
  }

  // final row-sum reduction across the 16 r-lanes
  #pragma unroll
  for (int d = 1; d < 16; d <<= 1) {
    #pragma unroll
    for (int mq = 0; mq < 2; ++mq)
      #pragma unroll
      for (int j = 0; j < 4; ++j) lsum[mq][j] += __shfl_xor(lsum[mq][j], d);
  }
  #pragma unroll
  for (int mq = 0; mq < 2; ++mq) {
    float rcp[4];
    #pragma unroll
    for (int j = 0; j < 4; ++j) rcp[j] = 1.0f / lsum[mq][j];
    #pragma unroll
    for (int n = 0; n < 4; ++n) {
      #pragma unroll
      for (int j = 0; j < 4; ++j) {
        int q = qt*128 + w*32 + mq*16 + kg*4 + j;
        int d = h*HDIM + n*16 + r;
        ob[(size_t)(b*SEQ + q) * D_MODEL + d] = f2bf(oacc[mq][n][j] * rcp[j]);
      }
    }
  }
}

// ---------------- launch ----------------
extern "C" void kernel_launch(void* const* d_in, const int* in_sizes, int n_in,
                              void* d_out, int out_size, void* d_ws, size_t ws_size,
                              hipStream_t stream) {
  const float* x   = (const float*)d_in[0];
  const int*  mask = (const int*)d_in[1];
  const float* Wq = (const float*)d_in[2];  const float* bq = (const float*)d_in[3];
  const float* Wk = (const float*)d_in[4];  const float* bk = (const float*)d_in[5];
  const float* Wv = (const float*)d_in[6];  const float* bv = (const float*)d_in[7];
  const float* Wo = (const float*)d_in[8];  const float* bo = (const float*)d_in[9];
  const float* W1 = (const float*)d_in[10]; const float* b1 = (const float*)d_in[11];
  const float* W2 = (const float*)d_in[12]; const float* b2 = (const float*)d_in[13];
  const float* g1 = (const float*)d_in[14]; const float* be1 = (const float*)d_in[15];
  const float* g2 = (const float*)d_in[16]; const float* be2 = (const float*)d_in[17];

  const size_t MB = 1u << 20;
  char* ws = (char*)d_ws;
  u16*  hln  = (u16*)(ws);              // 16MB  (LN1 out; later reused: vt, then LN2 out)
  u16*  vt   = (u16*)(ws);              // 16MB  V^T [b,h,d,key] — overwrites hln after QKV
  u16*  qb   = (u16*)(ws + 16*MB);      // 16MB
  u16*  kb   = (u16*)(ws + 32*MB);      // 16MB
  u16*  vb   = (u16*)(ws + 48*MB);      // 16MB
  u16*  attn = (u16*)(ws + 64*MB);      // 16MB
  u16*  ff1  = (u16*)(ws + 16*MB);      // 64MB, reuses q/k/v/attn region
  float* x2  = (float*)(ws + 80*MB);    // 32MB
  u16*  WqkvT= (u16*)(ws + 112*MB);     // 6MB contiguous: [3072][1024] (q|k|v)
  u16*  WqT  = WqkvT;
  u16*  WkT  = (u16*)(ws + 114*MB);
  u16*  WvT  = (u16*)(ws + 116*MB);
  u16*  WoT  = (u16*)(ws + 118*MB);
  u16*  W1T  = (u16*)(ws + 120*MB);     // [4096,1024] 8MB
  u16*  W2T  = (u16*)(ws + 128*MB);     // [1024,4096] 8MB

  dim3 tb(256);
  wt_kernel<<<dim3(1024/32, 1024/32), tb, 0, stream>>>(Wq, WqT, 1024, 1024);
  wt_kernel<<<dim3(1024/32, 1024/32), tb, 0, stream>>>(Wk, WkT, 1024, 1024);
  wt_kernel<<<dim3(1024/32, 1024/32), tb, 0, stream>>>(Wv, WvT, 1024, 1024);
  wt_kernel<<<dim3(1024/32, 1024/32), tb, 0, stream>>>(Wo, WoT, 1024, 1024);
  wt_kernel<<<dim3(4096/32, 1024/32), tb, 0, stream>>>(W1, W1T, 1024, 4096);
  wt_kernel<<<dim3(1024/32, 4096/32), tb, 0, stream>>>(W2, W2T, 4096, 1024);

  ln_kernel<<<ROWS, tb, 0, stream>>>(x, g1, be1, hln);

  dim3 gb(512);
  // fused QKV: one GEMM over [3072][1024] weights, routed epilogue
  gemm256<3><<<dim3(3072/256, ROWS/128), gb, 0, stream>>>(hln, WqkvT, bq, nullptr, qb,
                                                          ROWS, 3072, 1024,
                                                          bk, bv, kb, vb);

  vtrans_kernel<<<dim3(SEQ/64, BATCH*NHEAD), tb, 0, stream>>>(vb, vt);

  attn_kernel<<<dim3(SEQ/128, BATCH*NHEAD), tb, 0, stream>>>(qb, kb, vt, mask, attn);

  gemm256<1><<<dim3(1024/256, ROWS/128), gb, 0, stream>>>(attn, WoT, bo, x, x2,
                                                          ROWS, 1024, 1024,
                                                          nullptr, nullptr, nullptr, nullptr);

  ln_kernel<<<ROWS, tb, 0, stream>>>(x2, g2, be2, hln);

  gemm256<2><<<dim3(4096/256, ROWS/128), gb, 0, stream>>>(hln, W1T, b1, nullptr, ff1,
                                                          ROWS, 4096, 1024,
                                                          nullptr, nullptr, nullptr, nullptr);

  gemm256<1><<<dim3(1024/256, ROWS/128), gb, 0, stream>>>(ff1, W2T, b2, x2, (float*)d_out,
                                                          ROWS, 1024, 4096,
                                                          nullptr, nullptr, nullptr, nullptr);
}

// Round 5
// 460.572 us; speedup vs baseline: 1.1036x; 1.1036x over previous
//
#include <hip/hip_runtime.h>
#include <stdint.h>

#define D_MODEL 1024
#define NHEAD   16
#define HDIM    64
#define FFDIM   4096
#define BATCH   4
#define SEQ     2048
#define ROWS    (BATCH*SEQ)   // 8192

typedef unsigned short u16;
typedef __bf16 bf16_t;
typedef bf16_t bf16x8 __attribute__((ext_vector_type(8)));
typedef float  f32x4  __attribute__((ext_vector_type(4)));

#define SCQ 0.18033688011112042f   // 0.125 * log2(e) — folded into Q at QKV epilogue

__device__ __forceinline__ u16 f2bf(float f) {
  union { float f; unsigned u; } v; v.f = f;
  unsigned r = v.u + 0x7fffu + ((v.u >> 16) & 1u);
  return (u16)(r >> 16);
}

__device__ __forceinline__ void gl2lds16(const void* g, void* l) {
  __builtin_amdgcn_global_load_lds((const __attribute__((address_space(1))) void*)g,
                                   (__attribute__((address_space(3))) void*)l, 16, 0, 0);
}

#define MFMA_BF16(a, b, c) __builtin_amdgcn_mfma_f32_16x16x32_bf16((a), (b), (c), 0, 0, 0)
#define EXP2(x) __builtin_amdgcn_exp2f(x)

// ---------------- LayerNorm (fp32 in -> bf16 out) ----------------
__global__ __launch_bounds__(256) void ln_kernel(const float* __restrict__ x,
                                                 const float* __restrict__ g,
                                                 const float* __restrict__ be,
                                                 u16* __restrict__ out) {
  __shared__ float red[10];
  int row = blockIdx.x;
  int t = threadIdx.x;
  const float* xr = x + (size_t)row * D_MODEL;
  float4 xv = ((const float4*)xr)[t];
  float s  = xv.x + xv.y + xv.z + xv.w;
  float s2 = xv.x*xv.x + xv.y*xv.y + xv.z*xv.z + xv.w*xv.w;
  for (int d = 32; d > 0; d >>= 1) { s += __shfl_down(s, d); s2 += __shfl_down(s2, d); }
  int wid = t >> 6;
  if ((t & 63) == 0) { red[wid*2] = s; red[wid*2+1] = s2; }
  __syncthreads();
  if (t == 0) {
    float a = 0.f, b2 = 0.f;
    for (int i = 0; i < 4; ++i) { a += red[i*2]; b2 += red[i*2+1]; }
    red[8] = a; red[9] = b2;
  }
  __syncthreads();
  float mu  = red[8] * (1.0f / D_MODEL);
  float var = red[9] * (1.0f / D_MODEL) - mu*mu;
  float rstd = rsqrtf(var + 1e-12f);
  float4 gv = ((const float4*)g)[t];
  float4 bv = ((const float4*)be)[t];
  unsigned long long o =
      (unsigned long long)f2bf((xv.x - mu) * rstd * gv.x + bv.x)
    | ((unsigned long long)f2bf((xv.y - mu) * rstd * gv.y + bv.y) << 16)
    | ((unsigned long long)f2bf((xv.z - mu) * rstd * gv.z + bv.z) << 32)
    | ((unsigned long long)f2bf((xv.w - mu) * rstd * gv.w + bv.w) << 48);
  ((unsigned long long*)out)[(size_t)row * (D_MODEL/4) + t] = o;
}

// ---------------- Weight transpose fp32 [K,N] -> bf16 [N,K] ----------------
__global__ __launch_bounds__(256) void wt_kernel(const float* __restrict__ W,
                                                 u16* __restrict__ Wt, int K, int N) {
  __shared__ float tile[32][33];
  int n0 = blockIdx.x * 32, k0 = blockIdx.y * 32;
  int tx = threadIdx.x & 31, ty = threadIdx.x >> 5;   // ty: 0..7
  #pragma unroll
  for (int i = 0; i < 4; ++i) {
    int k = ty + i*8;
    tile[k][tx] = W[(size_t)(k0 + k) * N + n0 + tx];
  }
  __syncthreads();
  #pragma unroll
  for (int i = 0; i < 4; ++i) {
    int n = ty + i*8;
    Wt[(size_t)(n0 + n) * K + k0 + tx] = f2bf(tile[tx][n]);
  }
}

// ---------------- V transpose: [b,key,h,d] bf16 -> [b,h,d,key] bf16 --------
__global__ __launch_bounds__(256) void vtrans_kernel(const u16* __restrict__ vb,
                                                     u16* __restrict__ vt) {
  __shared__ __align__(16) u16 tile[64][80];
  int kb = blockIdx.x * 64;       // key block
  int bh = blockIdx.y;            // b*16+h
  int b = bh >> 4, h = bh & 15;
  int t = threadIdx.x;
  int key = t >> 2, dq = (t & 3) * 16;
  const u16* src = vb + (size_t)b*SEQ*D_MODEL + (size_t)(kb+key)*D_MODEL + h*HDIM + dq;
  *(bf16x8*)&tile[key][dq]     = *(const bf16x8*)(src);
  *(bf16x8*)&tile[key][dq + 8] = *(const bf16x8*)(src + 8);
  __syncthreads();
  int w = t >> 6, lane = t & 63;
  int kq = w * 16;
  u16 vals[16];
  #pragma unroll
  for (int e = 0; e < 16; ++e) vals[e] = tile[kq + e][lane];
  u16* dst = vt + (size_t)bh * HDIM * SEQ + (size_t)lane * SEQ + kb + kq;
  *(bf16x8*)dst       = *(const bf16x8*)&vals[0];
  *(bf16x8*)(dst + 8) = *(const bf16x8*)&vals[8];
}

// ---------------- GEMM 128x256, BK=64, tri-buffered, counted vmcnt ---------
// EPI 0: bf16 out = C + bias
// EPI 1: f32  out = resid + C + bias
// EPI 2: bf16 out = gelu(C + bias)
// EPI 3: QKV fused: N=3072; route by section bn>>2 to outp/out2/out3 with
//        bias/bias2/bias3; q section pre-scaled by SCQ. Output stride 1024.
__device__ __forceinline__ float gelu_f(float v) {
  return 0.5f * v * (1.0f + erff(v * 0.70710678118654752f));
}

template<int EPI>
__global__ __launch_bounds__(512, 2) void gemm256(const u16* __restrict__ A,
                                                  const u16* __restrict__ Bt,
                                                  const float* __restrict__ bias,
                                                  const float* __restrict__ resid,
                                                  void* __restrict__ outp,
                                                  int M, int N, int K,
                                                  const float* __restrict__ bias2,
                                                  const float* __restrict__ bias3,
                                                  void* __restrict__ out2,
                                                  void* __restrict__ out3) {
  __shared__ __align__(16) u16 sA[3][128*64];   // 48 KiB
  __shared__ __align__(16) u16 sB[3][256*64];   // 96 KiB
  const int tid = threadIdx.x;
  const int lane = tid & 63, w = tid >> 6;
  const int r = lane & 15, kg = lane >> 4, r7 = r & 7;
  const int wr = w >> 2, wc = w & 3;

  // XCD-aware bijective swizzle (all launches have nwg % 8 == 0)
  const int gx = gridDim.x;
  const int nwg = gx * gridDim.y;
  const int orig = blockIdx.y * gx + blockIdx.x;
  const int lid = (orig & 7) * (nwg >> 3) + (orig >> 3);
  const int bm = lid / gx, bn = lid % gx;

  const int NT = K >> 6;

  size_t offA[2], offB[4];
  #pragma unroll
  for (int u = 0; u < 2; ++u) {
    int slot = u*512 + tid;
    int row = slot >> 3, g = slot & 7;
    offA[u] = (size_t)(bm*128 + row) * K + ((g ^ (row & 7)) * 8);
  }
  #pragma unroll
  for (int u = 0; u < 4; ++u) {
    int slot = u*512 + tid;
    int row = slot >> 3, g = slot & 7;
    offB[u] = (size_t)(bn*256 + row) * K + ((g ^ (row & 7)) * 8);
  }

  f32x4 acc[4][4];
  #pragma unroll
  for (int m = 0; m < 4; ++m)
    #pragma unroll
    for (int n = 0; n < 4; ++n) acc[m][n] = f32x4{0.f, 0.f, 0.f, 0.f};

  // per-section routing for EPI 3 (wave-uniform: bn 0-3 q, 4-7 k, 8-11 v)
  const float* bsel = bias;
  u16* osel = (u16*)outp;
  int bnl = bn;
  float qscale = 1.0f;
  if (EPI == 3) {
    int sec = bn >> 2;
    bsel = (sec == 0) ? bias : (sec == 1 ? bias2 : bias3);
    osel = (u16*)((sec == 0) ? outp : (sec == 1 ? out2 : out3));
    if (sec == 0) qscale = SCQ;
    bnl = bn & 3;
  }
  float bv4[4];
  #pragma unroll
  for (int n = 0; n < 4; ++n) bv4[n] = bsel[bnl*256 + wc*64 + n*16 + r];

  // ---- prologue: stage K-tiles 0 and 1 ----
  #pragma unroll
  for (int u = 0; u < 2; ++u) gl2lds16(A  + offA[u],      &sA[0][(u*512+tid)*8]);
  #pragma unroll
  for (int u = 0; u < 4; ++u) gl2lds16(Bt + offB[u],      &sB[0][(u*512+tid)*8]);
  #pragma unroll
  for (int u = 0; u < 2; ++u) gl2lds16(A  + offA[u] + 64, &sA[1][(u*512+tid)*8]);
  #pragma unroll
  for (int u = 0; u < 4; ++u) gl2lds16(Bt + offB[u] + 64, &sB[1][(u*512+tid)*8]);
  asm volatile("s_waitcnt vmcnt(6)" ::: "memory");
  __builtin_amdgcn_s_barrier();

  int buf = 0;
  for (int t = 0; t < NT; ++t) {
    const bool pre = (t + 2 < NT);
    int nb = buf + 2; if (nb >= 3) nb -= 3;
    const size_t koff = (size_t)(t + 2) * 64;

    // ======== phase 0 (k-slice 0) ========
    bf16x8 af0[4], bf0[4];
    #pragma unroll
    for (int m = 0; m < 4; ++m)
      af0[m] = *(const bf16x8*)&sA[buf][(wr*64 + m*16 + r)*64 + ((kg ^ r7) * 8)];
    #pragma unroll
    for (int n = 0; n < 4; ++n)
      bf0[n] = *(const bf16x8*)&sB[buf][(wc*64 + n*16 + r)*64 + ((kg ^ r7) * 8)];
    if (pre) {
      gl2lds16(A  + offA[0] + koff, &sA[nb][(0*512+tid)*8]);
      gl2lds16(A  + offA[1] + koff, &sA[nb][(1*512+tid)*8]);
      gl2lds16(Bt + offB[0] + koff, &sB[nb][(0*512+tid)*8]);
    }
    __builtin_amdgcn_s_barrier();
    asm volatile("s_waitcnt lgkmcnt(0)" ::: "memory");
    __builtin_amdgcn_s_setprio(1);
    #pragma unroll
    for (int m = 0; m < 4; ++m)
      #pragma unroll
      for (int n = 0; n < 4; ++n)
        acc[m][n] = MFMA_BF16(af0[m], bf0[n], acc[m][n]);
    __builtin_amdgcn_s_setprio(0);
    __builtin_amdgcn_s_barrier();

    // ======== phase 1 (k-slice 1) ========
    bf16x8 af1[4], bf1[4];
    #pragma unroll
    for (int m = 0; m < 4; ++m)
      af1[m] = *(const bf16x8*)&sA[buf][(wr*64 + m*16 + r)*64 + (((4 + kg) ^ r7) * 8)];
    #pragma unroll
    for (int n = 0; n < 4; ++n)
      bf1[n] = *(const bf16x8*)&sB[buf][(wc*64 + n*16 + r)*64 + (((4 + kg) ^ r7) * 8)];
    if (pre) {
      gl2lds16(Bt + offB[1] + koff, &sB[nb][(1*512+tid)*8]);
      gl2lds16(Bt + offB[2] + koff, &sB[nb][(2*512+tid)*8]);
      gl2lds16(Bt + offB[3] + koff, &sB[nb][(3*512+tid)*8]);
    }
    __builtin_amdgcn_s_barrier();
    asm volatile("s_waitcnt lgkmcnt(0)" ::: "memory");
    __builtin_amdgcn_s_setprio(1);
    #pragma unroll
    for (int m = 0; m < 4; ++m)
      #pragma unroll
      for (int n = 0; n < 4; ++n)
        acc[m][n] = MFMA_BF16(af1[m], bf1[n], acc[m][n]);
    __builtin_amdgcn_s_setprio(0);
    if (pre) asm volatile("s_waitcnt vmcnt(6)" ::: "memory");
    else     asm volatile("s_waitcnt vmcnt(0)" ::: "memory");
    __builtin_amdgcn_s_barrier();
    buf += 1; if (buf >= 3) buf -= 3;
  }

  // ---- epilogue ----
  const int orow = bm*128 + wr*64;
  const int ocol = (EPI == 3 ? bnl : bn)*256 + wc*64;
  const int ostride = (EPI == 3) ? 1024 : N;
  #pragma unroll
  for (int m = 0; m < 4; ++m) {
    #pragma unroll
    for (int n = 0; n < 4; ++n) {
      #pragma unroll
      for (int j = 0; j < 4; ++j) {
        int rr = orow + m*16 + kg*4 + j;
        int cc = ocol + n*16 + r;
        size_t idx = (size_t)rr * ostride + cc;
        float v = acc[m][n][j] + bv4[n];
        if (EPI == 0)       ((u16*)outp)[idx]   = f2bf(v);
        else if (EPI == 1)  ((float*)outp)[idx] = resid[idx] + v;
        else if (EPI == 2)  ((u16*)outp)[idx]   = f2bf(gelu_f(v));
        else                osel[idx]           = f2bf(v * qscale);
      }
    }
  }
}

// ---------------- Flash attention: 4 waves/block, QBLK=16/wave, KVBLK=64 ---
// Q pre-scaled by SCQ (scores arrive in exp2 domain). exp2 via v_exp_f32.
// Mask fast-path skips selects when the wave's 64 keys are all unmasked.
__global__ __launch_bounds__(256) void attn_kernel(const u16* __restrict__ qb,
                                                   const u16* __restrict__ kb,
                                                   const u16* __restrict__ vt,
                                                   const int* __restrict__ mask,
                                                   u16* __restrict__ ob) {
  __shared__ __align__(16) u16 sK[2][64*64];
  __shared__ __align__(16) u16 sV[2][64*64];
  __shared__ __align__(16) bf16_t sP[4][16*64];
  const float THR2 = 11.541560327111708f;    // 8 * log2(e)
  int tid = threadIdx.x;
  int lane = tid & 63, w = tid >> 6;
  int r = lane & 15, kg = lane >> 4;
  int r7 = r & 7;
  int qt = blockIdx.x;
  int bh = blockIdx.y;
  int b = bh >> 4, h = bh & 15;
  size_t qkbase = (size_t)b * SEQ * D_MODEL + (size_t)h * HDIM;
  const u16* vtb = vt + (size_t)bh * HDIM * SEQ;
  const int* mrow = mask + b * SEQ;

  const u16* qrow = qb + qkbase + (size_t)(qt*64 + w*16 + r) * D_MODEL + kg*8;
  bf16x8 qf[2];
  qf[0] = *(const bf16x8*)(qrow);
  qf[1] = *(const bf16x8*)(qrow + 32);

  f32x4 oacc[4];
  #pragma unroll
  for (int n = 0; n < 4; ++n) oacc[n] = f32x4{0.f, 0.f, 0.f, 0.f};
  float m_run[4] = {-1e30f, -1e30f, -1e30f, -1e30f};
  float lsum[4]  = {0.f, 0.f, 0.f, 0.f};

  // staging pointers (strength-reduced): chunk c0 = w*64+lane, c1 = +256
  int ch0 = w*64 + lane, ch1 = ch0 + 256;
  int row0 = ch0 >> 3, col0 = ((ch0 & 7) ^ (row0 & 7)) * 8;
  int row1 = ch1 >> 3, col1 = ((ch1 & 7) ^ (row1 & 7)) * 8;
  const u16* kp0 = kb + qkbase + (size_t)row0 * D_MODEL + col0;
  const u16* kp1 = kb + qkbase + (size_t)row1 * D_MODEL + col1;
  const u16* vp0 = vtb + (size_t)row0 * SEQ + col0;
  const u16* vp1 = vtb + (size_t)row1 * SEQ + col1;

  const int NT = SEQ / 64;

  // prologue stage tile 0
  gl2lds16(kp0, &sK[0][ch0*8]);
  gl2lds16(kp1, &sK[0][ch1*8]);
  gl2lds16(vp0, &sV[0][ch0*8]);
  gl2lds16(vp1, &sV[0][ch1*8]);
  kp0 += 64*D_MODEL; kp1 += 64*D_MODEL; vp0 += 64; vp1 += 64;

  #pragma unroll 2
  for (int kt = 0; kt < NT; ++kt) {
    int cur = kt & 1;
    int key0 = kt * 64;
    if (kt + 1 < NT) {
      gl2lds16(kp0, &sK[cur^1][ch0*8]);
      gl2lds16(kp1, &sK[cur^1][ch1*8]);
      gl2lds16(vp0, &sV[cur^1][ch0*8]);
      gl2lds16(vp1, &sV[cur^1][ch1*8]);
      kp0 += 64*D_MODEL; kp1 += 64*D_MODEL; vp0 += 64; vp1 += 64;
      asm volatile("s_waitcnt vmcnt(4)" ::: "memory");
    } else {
      asm volatile("s_waitcnt vmcnt(0)" ::: "memory");
    }
    __builtin_amdgcn_s_barrier();

    const u16* Kt = sK[cur];
    const u16* Vt = sV[cur];

    // ---- QK^T (scores already in exp2 domain via pre-scaled Q) ----
    f32x4 s[4];
    #pragma unroll
    for (int n = 0; n < 4; ++n) s[n] = f32x4{0.f, 0.f, 0.f, 0.f};
    #pragma unroll
    for (int c = 0; c < 2; ++c) {
      #pragma unroll
      for (int n = 0; n < 4; ++n) {
        bf16x8 kf = *(const bf16x8*)&Kt[(n*16 + r)*64 + (((c*4 + kg) ^ r7) * 8)];
        s[n] = MFMA_BF16(qf[c], kf, s[n]);
      }
    }

    // ---- mask fast-path ----
    int mk[4];
    #pragma unroll
    for (int n = 0; n < 4; ++n) mk[n] = mrow[key0 + n*16 + r];
    if (!__all((mk[0] & mk[1] & mk[2] & mk[3]) != 0)) {
      #pragma unroll
      for (int n = 0; n < 4; ++n)
        #pragma unroll
        for (int j = 0; j < 4; ++j)
          s[n][j] = mk[n] ? s[n][j] : -1e9f;
    }
    float tm[4];
    #pragma unroll
    for (int n = 0; n < 4; ++n)
      #pragma unroll
      for (int j = 0; j < 4; ++j)
        tm[j] = (n == 0) ? s[n][j] : fmaxf(tm[j], s[n][j]);

    // ---- defer-max rescale (rare) ----
    bool grow = (tm[0] > m_run[0] + THR2) | (tm[1] > m_run[1] + THR2) |
                (tm[2] > m_run[2] + THR2) | (tm[3] > m_run[3] + THR2);
    if (__any(grow)) {
      #pragma unroll
      for (int d = 1; d < 16; d <<= 1) {
        #pragma unroll
        for (int j = 0; j < 4; ++j) tm[j] = fmaxf(tm[j], __shfl_xor(tm[j], d));
      }
      #pragma unroll
      for (int j = 0; j < 4; ++j) {
        float mn = fmaxf(m_run[j], tm[j]);
        float al = EXP2(m_run[j] - mn);
        m_run[j] = mn;
        lsum[j] *= al;
        oacc[0][j] *= al; oacc[1][j] *= al; oacc[2][j] *= al; oacc[3][j] *= al;
      }
    }
    // ---- P = exp2(s - m); lane-local row-sum; per-wave LDS (swizzled) ----
    bf16_t* pw = sP[w];
    #pragma unroll
    for (int n = 0; n < 4; ++n) {
      int cg = n*2 + (r >> 3);
      #pragma unroll
      for (int j = 0; j < 4; ++j) {
        float p = EXP2(s[n][j] - m_run[j]);
        lsum[j] += p;
        int row = kg*4 + j;
        pw[row*64 + ((cg ^ (row & 7)) * 8) + r7] = (bf16_t)p;
      }
    }
    bf16x8 pa[2];
    #pragma unroll
    for (int c = 0; c < 2; ++c)
      pa[c] = *(const bf16x8*)&sP[w][r*64 + (((c*4 + kg) ^ r7) * 8)];
    #pragma unroll
    for (int n = 0; n < 4; ++n) {
      #pragma unroll
      for (int c = 0; c < 2; ++c) {
        bf16x8 vf = *(const bf16x8*)&Vt[(n*16 + r)*64 + (((c*4 + kg) ^ r7) * 8)];
        oacc[n] = MFMA_BF16(pa[c], vf, oacc[n]);
      }
    }
    __builtin_amdgcn_s_barrier();
  }

  #pragma unroll
  for (int d = 1; d < 16; d <<= 1) {
    #pragma unroll
    for (int j = 0; j < 4; ++j) lsum[j] += __shfl_xor(lsum[j], d);
  }
  float rcp[4];
  #pragma unroll
  for (int j = 0; j < 4; ++j) rcp[j] = 1.0f / lsum[j];
  #pragma unroll
  for (int n = 0; n < 4; ++n) {
    #pragma unroll
    for (int j = 0; j < 4; ++j) {
      int q = qt*64 + w*16 + kg*4 + j;
      int d = h*HDIM + n*16 + r;
      ob[(size_t)(b*SEQ + q) * D_MODEL + d] = f2bf(oacc[n][j] * rcp[j]);
    }
  }
}

// ---------------- launch ----------------
extern "C" void kernel_launch(void* const* d_in, const int* in_sizes, int n_in,
                              void* d_out, int out_size, void* d_ws, size_t ws_size,
                              hipStream_t stream) {
  const float* x   = (const float*)d_in[0];
  const int*  mask = (const int*)d_in[1];
  const float* Wq = (const float*)d_in[2];  const float* bq = (const float*)d_in[3];
  const float* Wk = (const float*)d_in[4];  const float* bk = (const float*)d_in[5];
  const float* Wv = (const float*)d_in[6];  const float* bv = (const float*)d_in[7];
  const float* Wo = (const float*)d_in[8];  const float* bo = (const float*)d_in[9];
  const float* W1 = (const float*)d_in[10]; const float* b1 = (const float*)d_in[11];
  const float* W2 = (const float*)d_in[12]; const float* b2 = (const float*)d_in[13];
  const float* g1 = (const float*)d_in[14]; const float* be1 = (const float*)d_in[15];
  const float* g2 = (const float*)d_in[16]; const float* be2 = (const float*)d_in[17];

  const size_t MB = 1u << 20;
  char* ws = (char*)d_ws;
  u16*  hln  = (u16*)(ws);              // 16MB  (LN1 out; later reused: vt, then LN2 out)
  u16*  vt   = (u16*)(ws);              // 16MB  V^T [b,h,d,key] — overwrites hln after QKV
  u16*  qb   = (u16*)(ws + 16*MB);      // 16MB
  u16*  kb   = (u16*)(ws + 32*MB);      // 16MB
  u16*  vb   = (u16*)(ws + 48*MB);      // 16MB
  u16*  attn = (u16*)(ws + 64*MB);      // 16MB
  u16*  ff1  = (u16*)(ws + 16*MB);      // 64MB, reuses q/k/v/attn region
  float* x2  = (float*)(ws + 80*MB);    // 32MB
  u16*  WqkvT= (u16*)(ws + 112*MB);     // 6MB contiguous: [3072][1024] (q|k|v)
  u16*  WqT  = WqkvT;
  u16*  WkT  = (u16*)(ws + 114*MB);
  u16*  WvT  = (u16*)(ws + 116*MB);
  u16*  WoT  = (u16*)(ws + 118*MB);
  u16*  W1T  = (u16*)(ws + 120*MB);     // [4096,1024] 8MB
  u16*  W2T  = (u16*)(ws + 128*MB);     // [1024,4096] 8MB

  dim3 tb(256);
  wt_kernel<<<dim3(1024/32, 1024/32), tb, 0, stream>>>(Wq, WqT, 1024, 1024);
  wt_kernel<<<dim3(1024/32, 1024/32), tb, 0, stream>>>(Wk, WkT, 1024, 1024);
  wt_kernel<<<dim3(1024/32, 1024/32), tb, 0, stream>>>(Wv, WvT, 1024, 1024);
  wt_kernel<<<dim3(1024/32, 1024/32), tb, 0, stream>>>(Wo, WoT, 1024, 1024);
  wt_kernel<<<dim3(4096/32, 1024/32), tb, 0, stream>>>(W1, W1T, 1024, 4096);
  wt_kernel<<<dim3(1024/32, 4096/32), tb, 0, stream>>>(W2, W2T, 4096, 1024);

  ln_kernel<<<ROWS, tb, 0, stream>>>(x, g1, be1, hln);

  dim3 gb(512);
  // fused QKV: one GEMM over [3072][1024] weights, routed epilogue (q pre-scaled)
  gemm256<3><<<dim3(3072/256, ROWS/128), gb, 0, stream>>>(hln, WqkvT, bq, nullptr, qb,
                                                          ROWS, 3072, 1024,
                                                          bk, bv, kb, vb);

  vtrans_kernel<<<dim3(SEQ/64, BATCH*NHEAD), tb, 0, stream>>>(vb, vt);

  attn_kernel<<<dim3(SEQ/64, BATCH*NHEAD), tb, 0, stream>>>(qb, kb, vt, mask, attn);

  gemm256<1><<<dim3(1024/256, ROWS/128), gb, 0, stream>>>(attn, WoT, bo, x, x2,
                                                          ROWS, 1024, 1024,
                                                          nullptr, nullptr, nullptr, nullptr);

  ln_kernel<<<ROWS, tb, 0, stream>>>(x2, g2, be2, hln);

  gemm256<2><<<dim3(4096/256, ROWS/128), gb, 0, stream>>>(hln, W1T, b1, nullptr, ff1,
                                                          ROWS, 4096, 1024,
                                                          nullptr, nullptr, nullptr, nullptr);

  gemm256<1><<<dim3(1024/256, ROWS/128), gb, 0, stream>>>(ff1, W2T, b2, x2, (float*)d_out,
                                                          ROWS, 1024, 4096,
                                                          nullptr, nullptr, nullptr, nullptr);
}

// Round 6
// 437.956 us; speedup vs baseline: 1.1606x; 1.0516x over previous
//
#include <hip/hip_runtime.h>
#include <stdint.h>

#define D_MODEL 1024
#define NHEAD   16
#define HDIM    64
#define FFDIM   4096
#define BATCH   4
#define SEQ     2048
#define ROWS    (BATCH*SEQ)   // 8192

typedef unsigned short u16;
typedef __bf16 bf16_t;
typedef bf16_t bf16x8 __attribute__((ext_vector_type(8)));
typedef float  f32x4  __attribute__((ext_vector_type(4)));

#define SCQ 0.18033688011112042f   // 0.125 * log2(e) — folded into Q at QKV epilogue

__device__ __forceinline__ u16 f2bf(float f) {
  union { float f; unsigned u; } v; v.f = f;
  unsigned r = v.u + 0x7fffu + ((v.u >> 16) & 1u);
  return (u16)(r >> 16);
}

__device__ __forceinline__ void gl2lds16(const void* g, void* l) {
  __builtin_amdgcn_global_load_lds((const __attribute__((address_space(1))) void*)g,
                                   (__attribute__((address_space(3))) void*)l, 16, 0, 0);
}

#define MFMA_BF16(a, b, c) __builtin_amdgcn_mfma_f32_16x16x32_bf16((a), (b), (c), 0, 0, 0)
#define EXP2(x) __builtin_amdgcn_exp2f(x)

// ---------------- LayerNorm (fp32 in -> bf16 out) ----------------
__global__ __launch_bounds__(256) void ln_kernel(const float* __restrict__ x,
                                                 const float* __restrict__ g,
                                                 const float* __restrict__ be,
                                                 u16* __restrict__ out) {
  __shared__ float red[10];
  int row = blockIdx.x;
  int t = threadIdx.x;
  const float* xr = x + (size_t)row * D_MODEL;
  float4 xv = ((const float4*)xr)[t];
  float s  = xv.x + xv.y + xv.z + xv.w;
  float s2 = xv.x*xv.x + xv.y*xv.y + xv.z*xv.z + xv.w*xv.w;
  for (int d = 32; d > 0; d >>= 1) { s += __shfl_down(s, d); s2 += __shfl_down(s2, d); }
  int wid = t >> 6;
  if ((t & 63) == 0) { red[wid*2] = s; red[wid*2+1] = s2; }
  __syncthreads();
  if (t == 0) {
    float a = 0.f, b2 = 0.f;
    for (int i = 0; i < 4; ++i) { a += red[i*2]; b2 += red[i*2+1]; }
    red[8] = a; red[9] = b2;
  }
  __syncthreads();
  float mu  = red[8] * (1.0f / D_MODEL);
  float var = red[9] * (1.0f / D_MODEL) - mu*mu;
  float rstd = rsqrtf(var + 1e-12f);
  float4 gv = ((const float4*)g)[t];
  float4 bv = ((const float4*)be)[t];
  unsigned long long o =
      (unsigned long long)f2bf((xv.x - mu) * rstd * gv.x + bv.x)
    | ((unsigned long long)f2bf((xv.y - mu) * rstd * gv.y + bv.y) << 16)
    | ((unsigned long long)f2bf((xv.z - mu) * rstd * gv.z + bv.z) << 32)
    | ((unsigned long long)f2bf((xv.w - mu) * rstd * gv.w + bv.w) << 48);
  ((unsigned long long*)out)[(size_t)row * (D_MODEL/4) + t] = o;
}

// ---------------- Weight transpose fp32 [K,N] -> bf16 [N,K] ----------------
__global__ __launch_bounds__(256) void wt_kernel(const float* __restrict__ W,
                                                 u16* __restrict__ Wt, int K, int N) {
  __shared__ float tile[32][33];
  int n0 = blockIdx.x * 32, k0 = blockIdx.y * 32;
  int tx = threadIdx.x & 31, ty = threadIdx.x >> 5;   // ty: 0..7
  #pragma unroll
  for (int i = 0; i < 4; ++i) {
    int k = ty + i*8;
    tile[k][tx] = W[(size_t)(k0 + k) * N + n0 + tx];
  }
  __syncthreads();
  #pragma unroll
  for (int i = 0; i < 4; ++i) {
    int n = ty + i*8;
    Wt[(size_t)(n0 + n) * K + k0 + tx] = f2bf(tile[tx][n]);
  }
}

// ---------------- V transpose: [b,key,h,d] bf16 -> [b,h,d,key] bf16 --------
__global__ __launch_bounds__(256) void vtrans_kernel(const u16* __restrict__ vb,
                                                     u16* __restrict__ vt) {
  __shared__ __align__(16) u16 tile[64][80];
  int kb = blockIdx.x * 64;       // key block
  int bh = blockIdx.y;            // b*16+h
  int b = bh >> 4, h = bh & 15;
  int t = threadIdx.x;
  int key = t >> 2, dq = (t & 3) * 16;
  const u16* src = vb + (size_t)b*SEQ*D_MODEL + (size_t)(kb+key)*D_MODEL + h*HDIM + dq;
  *(bf16x8*)&tile[key][dq]     = *(const bf16x8*)(src);
  *(bf16x8*)&tile[key][dq + 8] = *(const bf16x8*)(src + 8);
  __syncthreads();
  int w = t >> 6, lane = t & 63;
  int kq = w * 16;
  u16 vals[16];
  #pragma unroll
  for (int e = 0; e < 16; ++e) vals[e] = tile[kq + e][lane];
  u16* dst = vt + (size_t)bh * HDIM * SEQ + (size_t)lane * SEQ + kb + kq;
  *(bf16x8*)dst       = *(const bf16x8*)&vals[0];
  *(bf16x8*)(dst + 8) = *(const bf16x8*)&vals[8];
}

// ---------------- GEMM 128x256, BK=64, tri-buffered, pipelined frags -------
// Per K-tile: {ds_read slice1 | prefetch t+2 | MFMA slice0 | lgkm drain |
//  vmcnt(6) | barrier | ds_read next slice0 | MFMA slice1} — fragment reads
// always covered by the other slice's MFMA; single barrier per K-tile.
// EPI 0: bf16 out = C + bias
// EPI 1: f32  out = resid + C + bias
// EPI 2: bf16 out = gelu(C + bias)
// EPI 3: QKV fused: N=3072; route by section bn>>2; q pre-scaled by SCQ.
__device__ __forceinline__ float gelu_f(float v) {
  return 0.5f * v * (1.0f + erff(v * 0.70710678118654752f));
}

template<int EPI>
__global__ __launch_bounds__(512, 2) void gemm256(const u16* __restrict__ A,
                                                  const u16* __restrict__ Bt,
                                                  const float* __restrict__ bias,
                                                  const float* __restrict__ resid,
                                                  void* __restrict__ outp,
                                                  int M, int N, int K,
                                                  const float* __restrict__ bias2,
                                                  const float* __restrict__ bias3,
                                                  void* __restrict__ out2,
                                                  void* __restrict__ out3) {
  __shared__ __align__(16) u16 sA[3][128*64];   // 48 KiB
  __shared__ __align__(16) u16 sB[3][256*64];   // 96 KiB
  const int tid = threadIdx.x;
  const int lane = tid & 63, w = tid >> 6;
  const int r = lane & 15, kg = lane >> 4, r7 = r & 7;
  const int wr = w >> 2, wc = w & 3;

  // XCD-aware bijective swizzle (all launches have nwg % 8 == 0)
  const int gx = gridDim.x;
  const int nwg = gx * gridDim.y;
  const int orig = blockIdx.y * gx + blockIdx.x;
  const int lid = (orig & 7) * (nwg >> 3) + (orig >> 3);
  const int bm = lid / gx, bn = lid % gx;

  const int NT = K >> 6;

  size_t offA[2], offB[4];
  #pragma unroll
  for (int u = 0; u < 2; ++u) {
    int slot = u*512 + tid;
    int row = slot >> 3, g = slot & 7;
    offA[u] = (size_t)(bm*128 + row) * K + ((g ^ (row & 7)) * 8);
  }
  #pragma unroll
  for (int u = 0; u < 4; ++u) {
    int slot = u*512 + tid;
    int row = slot >> 3, g = slot & 7;
    offB[u] = (size_t)(bn*256 + row) * K + ((g ^ (row & 7)) * 8);
  }

  f32x4 acc[4][4];
  #pragma unroll
  for (int m = 0; m < 4; ++m)
    #pragma unroll
    for (int n = 0; n < 4; ++n) acc[m][n] = f32x4{0.f, 0.f, 0.f, 0.f};

  // per-section routing for EPI 3 (wave-uniform: bn 0-3 q, 4-7 k, 8-11 v)
  const float* bsel = bias;
  u16* osel = (u16*)outp;
  int bnl = bn;
  float qscale = 1.0f;
  if (EPI == 3) {
    int sec = bn >> 2;
    bsel = (sec == 0) ? bias : (sec == 1 ? bias2 : bias3);
    osel = (u16*)((sec == 0) ? outp : (sec == 1 ? out2 : out3));
    if (sec == 0) qscale = SCQ;
    bnl = bn & 3;
  }
  float bv4[4];
  #pragma unroll
  for (int n = 0; n < 4; ++n) bv4[n] = bsel[bnl*256 + wc*64 + n*16 + r];

  auto load_frags = [&](bf16x8 (&aa)[4], bf16x8 (&bb)[4], int bbuf, int sl) {
    #pragma unroll
    for (int m = 0; m < 4; ++m)
      aa[m] = *(const bf16x8*)&sA[bbuf][(wr*64 + m*16 + r)*64 + (((sl*4 + kg) ^ r7) * 8)];
    #pragma unroll
    for (int n = 0; n < 4; ++n)
      bb[n] = *(const bf16x8*)&sB[bbuf][(wc*64 + n*16 + r)*64 + (((sl*4 + kg) ^ r7) * 8)];
  };
  auto mfma16 = [&](bf16x8 (&aa)[4], bf16x8 (&bb)[4]) {
    __builtin_amdgcn_s_setprio(1);
    #pragma unroll
    for (int m = 0; m < 4; ++m)
      #pragma unroll
      for (int n = 0; n < 4; ++n)
        acc[m][n] = MFMA_BF16(aa[m], bb[n], acc[m][n]);
    __builtin_amdgcn_s_setprio(0);
  };

  // ---- prologue: stage K-tiles 0 and 1 ----
  #pragma unroll
  for (int u = 0; u < 2; ++u) gl2lds16(A  + offA[u],      &sA[0][(u*512+tid)*8]);
  #pragma unroll
  for (int u = 0; u < 4; ++u) gl2lds16(Bt + offB[u],      &sB[0][(u*512+tid)*8]);
  #pragma unroll
  for (int u = 0; u < 2; ++u) gl2lds16(A  + offA[u] + 64, &sA[1][(u*512+tid)*8]);
  #pragma unroll
  for (int u = 0; u < 4; ++u) gl2lds16(Bt + offB[u] + 64, &sB[1][(u*512+tid)*8]);
  asm volatile("s_waitcnt vmcnt(6)" ::: "memory");
  __builtin_amdgcn_s_barrier();

  bf16x8 a0[4], b0[4], a1[4], b1[4];
  load_frags(a0, b0, 0, 0);

  int buf = 0;
  for (int t = 0; t < NT - 1; ++t) {
    int nb = buf + 2; if (nb >= 3) nb -= 3;
    const bool pre = (t + 2 < NT);
    const size_t koff = (size_t)(t + 2) * 64;

    load_frags(a1, b1, buf, 1);          // slice-1 reads (covered by MFMA slice-0)
    if (pre) {
      gl2lds16(A  + offA[0] + koff, &sA[nb][(0*512+tid)*8]);
      gl2lds16(A  + offA[1] + koff, &sA[nb][(1*512+tid)*8]);
      gl2lds16(Bt + offB[0] + koff, &sB[nb][(0*512+tid)*8]);
      gl2lds16(Bt + offB[1] + koff, &sB[nb][(1*512+tid)*8]);
      gl2lds16(Bt + offB[2] + koff, &sB[nb][(2*512+tid)*8]);
      gl2lds16(Bt + offB[3] + koff, &sB[nb][(3*512+tid)*8]);
    }
    mfma16(a0, b0);                      // slice-0 MFMA
    // drain this tile's LDS reads before the barrier that precedes writes
    asm volatile("s_waitcnt lgkmcnt(0)" ::: "memory");
    __builtin_amdgcn_sched_barrier(0);
    if (pre) asm volatile("s_waitcnt vmcnt(6)" ::: "memory");
    else     asm volatile("s_waitcnt vmcnt(0)" ::: "memory");
    __builtin_amdgcn_s_barrier();

    int bnext = buf + 1; if (bnext >= 3) bnext -= 3;
    load_frags(a0, b0, bnext, 0);        // next tile slice-0 (covered by MFMA slice-1)
    mfma16(a1, b1);                      // slice-1 MFMA
    buf = bnext;
  }
  // tail: last tile's slice 1
  load_frags(a1, b1, buf, 1);
  mfma16(a0, b0);
  mfma16(a1, b1);

  // ---- epilogue ----
  const int orow = bm*128 + wr*64;
  const int ocol = (EPI == 3 ? bnl : bn)*256 + wc*64;
  const int ostride = (EPI == 3) ? 1024 : N;
  #pragma unroll
  for (int m = 0; m < 4; ++m) {
    #pragma unroll
    for (int n = 0; n < 4; ++n) {
      #pragma unroll
      for (int j = 0; j < 4; ++j) {
        int rr = orow + m*16 + kg*4 + j;
        int cc = ocol + n*16 + r;
        size_t idx = (size_t)rr * ostride + cc;
        float v = acc[m][n][j] + bv4[n];
        if (EPI == 0)       ((u16*)outp)[idx]   = f2bf(v);
        else if (EPI == 1)  ((float*)outp)[idx] = resid[idx] + v;
        else if (EPI == 2)  ((u16*)outp)[idx]   = f2bf(gelu_f(v));
        else                osel[idx]           = f2bf(v * qscale);
      }
    }
  }
}

// ---------------- Flash attention: 4 waves/block, QBLK=16/wave, KVBLK=64 ---
// Q pre-scaled by SCQ (scores arrive in exp2 domain). exp2 via v_exp_f32.
// Mask fast-path skips selects when the wave's 64 keys are all unmasked.
__global__ __launch_bounds__(256) void attn_kernel(const u16* __restrict__ qb,
                                                   const u16* __restrict__ kb,
                                                   const u16* __restrict__ vt,
                                                   const int* __restrict__ mask,
                                                   u16* __restrict__ ob) {
  __shared__ __align__(16) u16 sK[2][64*64];
  __shared__ __align__(16) u16 sV[2][64*64];
  __shared__ __align__(16) bf16_t sP[4][16*64];
  const float THR2 = 11.541560327111708f;    // 8 * log2(e)
  int tid = threadIdx.x;
  int lane = tid & 63, w = tid >> 6;
  int r = lane & 15, kg = lane >> 4;
  int r7 = r & 7;
  int qt = blockIdx.x;
  int bh = blockIdx.y;
  int b = bh >> 4, h = bh & 15;
  size_t qkbase = (size_t)b * SEQ * D_MODEL + (size_t)h * HDIM;
  const u16* vtb = vt + (size_t)bh * HDIM * SEQ;
  const int* mrow = mask + b * SEQ;

  const u16* qrow = qb + qkbase + (size_t)(qt*64 + w*16 + r) * D_MODEL + kg*8;
  bf16x8 qf[2];
  qf[0] = *(const bf16x8*)(qrow);
  qf[1] = *(const bf16x8*)(qrow + 32);

  f32x4 oacc[4];
  #pragma unroll
  for (int n = 0; n < 4; ++n) oacc[n] = f32x4{0.f, 0.f, 0.f, 0.f};
  float m_run[4] = {-1e30f, -1e30f, -1e30f, -1e30f};
  float lsum[4]  = {0.f, 0.f, 0.f, 0.f};

  // staging pointers (strength-reduced): chunk c0 = w*64+lane, c1 = +256
  int ch0 = w*64 + lane, ch1 = ch0 + 256;
  int row0 = ch0 >> 3, col0 = ((ch0 & 7) ^ (row0 & 7)) * 8;
  int row1 = ch1 >> 3, col1 = ((ch1 & 7) ^ (row1 & 7)) * 8;
  const u16* kp0 = kb + qkbase + (size_t)row0 * D_MODEL + col0;
  const u16* kp1 = kb + qkbase + (size_t)row1 * D_MODEL + col1;
  const u16* vp0 = vtb + (size_t)row0 * SEQ + col0;
  const u16* vp1 = vtb + (size_t)row1 * SEQ + col1;

  const int NT = SEQ / 64;

  // prologue stage tile 0
  gl2lds16(kp0, &sK[0][ch0*8]);
  gl2lds16(kp1, &sK[0][ch1*8]);
  gl2lds16(vp0, &sV[0][ch0*8]);
  gl2lds16(vp1, &sV[0][ch1*8]);
  kp0 += 64*D_MODEL; kp1 += 64*D_MODEL; vp0 += 64; vp1 += 64;

  #pragma unroll 2
  for (int kt = 0; kt < NT; ++kt) {
    int cur = kt & 1;
    int key0 = kt * 64;
    if (kt + 1 < NT) {
      gl2lds16(kp0, &sK[cur^1][ch0*8]);
      gl2lds16(kp1, &sK[cur^1][ch1*8]);
      gl2lds16(vp0, &sV[cur^1][ch0*8]);
      gl2lds16(vp1, &sV[cur^1][ch1*8]);
      kp0 += 64*D_MODEL; kp1 += 64*D_MODEL; vp0 += 64; vp1 += 64;
      asm volatile("s_waitcnt vmcnt(4)" ::: "memory");
    } else {
      asm volatile("s_waitcnt vmcnt(0)" ::: "memory");
    }
    __builtin_amdgcn_s_barrier();

    const u16* Kt = sK[cur];
    const u16* Vt = sV[cur];

    // ---- QK^T (scores already in exp2 domain via pre-scaled Q) ----
    f32x4 s[4];
    #pragma unroll
    for (int n = 0; n < 4; ++n) s[n] = f32x4{0.f, 0.f, 0.f, 0.f};
    #pragma unroll
    for (int c = 0; c < 2; ++c) {
      #pragma unroll
      for (int n = 0; n < 4; ++n) {
        bf16x8 kf = *(const bf16x8*)&Kt[(n*16 + r)*64 + (((c*4 + kg) ^ r7) * 8)];
        s[n] = MFMA_BF16(qf[c], kf, s[n]);
      }
    }

    // ---- mask fast-path ----
    int mk[4];
    #pragma unroll
    for (int n = 0; n < 4; ++n) mk[n] = mrow[key0 + n*16 + r];
    if (!__all((mk[0] & mk[1] & mk[2] & mk[3]) != 0)) {
      #pragma unroll
      for (int n = 0; n < 4; ++n)
        #pragma unroll
        for (int j = 0; j < 4; ++j)
          s[n][j] = mk[n] ? s[n][j] : -1e9f;
    }
    float tm[4];
    #pragma unroll
    for (int n = 0; n < 4; ++n)
      #pragma unroll
      for (int j = 0; j < 4; ++j)
        tm[j] = (n == 0) ? s[n][j] : fmaxf(tm[j], s[n][j]);

    // ---- defer-max rescale (rare) ----
    bool grow = (tm[0] > m_run[0] + THR2) | (tm[1] > m_run[1] + THR2) |
                (tm[2] > m_run[2] + THR2) | (tm[3] > m_run[3] + THR2);
    if (__any(grow)) {
      #pragma unroll
      for (int d = 1; d < 16; d <<= 1) {
        #pragma unroll
        for (int j = 0; j < 4; ++j) tm[j] = fmaxf(tm[j], __shfl_xor(tm[j], d));
      }
      #pragma unroll
      for (int j = 0; j < 4; ++j) {
        float mn = fmaxf(m_run[j], tm[j]);
        float al = EXP2(m_run[j] - mn);
        m_run[j] = mn;
        lsum[j] *= al;
        oacc[0][j] *= al; oacc[1][j] *= al; oacc[2][j] *= al; oacc[3][j] *= al;
      }
    }
    // ---- P = exp2(s - m); lane-local row-sum; per-wave LDS (swizzled) ----
    bf16_t* pw = sP[w];
    #pragma unroll
    for (int n = 0; n < 4; ++n) {
      int cg = n*2 + (r >> 3);
      #pragma unroll
      for (int j = 0; j < 4; ++j) {
        float p = EXP2(s[n][j] - m_run[j]);
        lsum[j] += p;
        int row = kg*4 + j;
        pw[row*64 + ((cg ^ (row & 7)) * 8) + r7] = (bf16_t)p;
      }
    }
    bf16x8 pa[2];
    #pragma unroll
    for (int c = 0; c < 2; ++c)
      pa[c] = *(const bf16x8*)&sP[w][r*64 + (((c*4 + kg) ^ r7) * 8)];
    #pragma unroll
    for (int n = 0; n < 4; ++n) {
      #pragma unroll
      for (int c = 0; c < 2; ++c) {
        bf16x8 vf = *(const bf16x8*)&Vt[(n*16 + r)*64 + (((c*4 + kg) ^ r7) * 8)];
        oacc[n] = MFMA_BF16(pa[c], vf, oacc[n]);
      }
    }
    __builtin_amdgcn_s_barrier();
  }

  #pragma unroll
  for (int d = 1; d < 16; d <<= 1) {
    #pragma unroll
    for (int j = 0; j < 4; ++j) lsum[j] += __shfl_xor(lsum[j], d);
  }
  float rcp[4];
  #pragma unroll
  for (int j = 0; j < 4; ++j) rcp[j] = 1.0f / lsum[j];
  #pragma unroll
  for (int n = 0; n < 4; ++n) {
    #pragma unroll
    for (int j = 0; j < 4; ++j) {
      int q = qt*64 + w*16 + kg*4 + j;
      int d = h*HDIM + n*16 + r;
      ob[(size_t)(b*SEQ + q) * D_MODEL + d] = f2bf(oacc[n][j] * rcp[j]);
    }
  }
}

// ---------------- launch ----------------
extern "C" void kernel_launch(void* const* d_in, const int* in_sizes, int n_in,
                              void* d_out, int out_size, void* d_ws, size_t ws_size,
                              hipStream_t stream) {
  const float* x   = (const float*)d_in[0];
  const int*  mask = (const int*)d_in[1];
  const float* Wq = (const float*)d_in[2];  const float* bq = (const float*)d_in[3];
  const float* Wk = (const float*)d_in[4];  const float* bk = (const float*)d_in[5];
  const float* Wv = (const float*)d_in[6];  const float* bv = (const float*)d_in[7];
  const float* Wo = (const float*)d_in[8];  const float* bo = (const float*)d_in[9];
  const float* W1 = (const float*)d_in[10]; const float* b1 = (const float*)d_in[11];
  const float* W2 = (const float*)d_in[12]; const float* b2 = (const float*)d_in[13];
  const float* g1 = (const float*)d_in[14]; const float* be1 = (const float*)d_in[15];
  const float* g2 = (const float*)d_in[16]; const float* be2 = (const float*)d_in[17];

  const size_t MB = 1u << 20;
  char* ws = (char*)d_ws;
  u16*  hln  = (u16*)(ws);              // 16MB  (LN1 out; later reused: vt, then LN2 out)
  u16*  vt   = (u16*)(ws);              // 16MB  V^T [b,h,d,key] — overwrites hln after QKV
  u16*  qb   = (u16*)(ws + 16*MB);      // 16MB
  u16*  kb   = (u16*)(ws + 32*MB);      // 16MB
  u16*  vb   = (u16*)(ws + 48*MB);      // 16MB
  u16*  attn = (u16*)(ws + 64*MB);      // 16MB
  u16*  ff1  = (u16*)(ws + 16*MB);      // 64MB, reuses q/k/v/attn region
  float* x2  = (float*)(ws + 80*MB);    // 32MB
  u16*  WqkvT= (u16*)(ws + 112*MB);     // 6MB contiguous: [3072][1024] (q|k|v)
  u16*  WqT  = WqkvT;
  u16*  WkT  = (u16*)(ws + 114*MB);
  u16*  WvT  = (u16*)(ws + 116*MB);
  u16*  WoT  = (u16*)(ws + 118*MB);
  u16*  W1T  = (u16*)(ws + 120*MB);     // [4096,1024] 8MB
  u16*  W2T  = (u16*)(ws + 128*MB);     // [1024,4096] 8MB

  dim3 tb(256);
  wt_kernel<<<dim3(1024/32, 1024/32), tb, 0, stream>>>(Wq, WqT, 1024, 1024);
  wt_kernel<<<dim3(1024/32, 1024/32), tb, 0, stream>>>(Wk, WkT, 1024, 1024);
  wt_kernel<<<dim3(1024/32, 1024/32), tb, 0, stream>>>(Wv, WvT, 1024, 1024);
  wt_kernel<<<dim3(1024/32, 1024/32), tb, 0, stream>>>(Wo, WoT, 1024, 1024);
  wt_kernel<<<dim3(4096/32, 1024/32), tb, 0, stream>>>(W1, W1T, 1024, 4096);
  wt_kernel<<<dim3(1024/32, 4096/32), tb, 0, stream>>>(W2, W2T, 4096, 1024);

  ln_kernel<<<ROWS, tb, 0, stream>>>(x, g1, be1, hln);

  dim3 gb(512);
  // fused QKV: one GEMM over [3072][1024] weights, routed epilogue (q pre-scaled)
  gemm256<3><<<dim3(3072/256, ROWS/128), gb, 0, stream>>>(hln, WqkvT, bq, nullptr, qb,
                                                          ROWS, 3072, 1024,
                                                          bk, bv, kb, vb);

  vtrans_kernel<<<dim3(SEQ/64, BATCH*NHEAD), tb, 0, stream>>>(vb, vt);

  attn_kernel<<<dim3(SEQ/64, BATCH*NHEAD), tb, 0, stream>>>(qb, kb, vt, mask, attn);

  gemm256<1><<<dim3(1024/256, ROWS/128), gb, 0, stream>>>(attn, WoT, bo, x, x2,
                                                          ROWS, 1024, 1024,
                                                          nullptr, nullptr, nullptr, nullptr);

  ln_kernel<<<ROWS, tb, 0, stream>>>(x2, g2, be2, hln);

  gemm256<2><<<dim3(4096/256, ROWS/128), gb, 0, stream>>>(hln, W1T, b1, nullptr, ff1,
                                                          ROWS, 4096, 1024,
                                                          nullptr, nullptr, nullptr, nullptr);

  gemm256<1><<<dim3(1024/256, ROWS/128), gb, 0, stream>>>(ff1, W2T, b2, x2, (float*)d_out,
                                                          ROWS, 1024, 4096,
                                                          nullptr, nullptr, nullptr, nullptr);
}

// Round 7
// 428.508 us; speedup vs baseline: 1.1862x; 1.0220x over previous
//
#include <hip/hip_runtime.h>
#include <stdint.h>

#define D_MODEL 1024
#define NHEAD   16
#define HDIM    64
#define FFDIM   4096
#define BATCH   4
#define SEQ     2048
#define ROWS    (BATCH*SEQ)   // 8192

typedef unsigned short u16;
typedef __bf16 bf16_t;
typedef bf16_t bf16x8 __attribute__((ext_vector_type(8)));
typedef float  f32x4  __attribute__((ext_vector_type(4)));

#define SCQ 0.18033688011112042f   // 0.125 * log2(e) — folded into Q at QKV epilogue

__device__ __forceinline__ u16 f2bf(float f) {
  union { float f; unsigned u; } v; v.f = f;
  unsigned r = v.u + 0x7fffu + ((v.u >> 16) & 1u);
  return (u16)(r >> 16);
}

__device__ __forceinline__ void gl2lds16(const void* g, void* l) {
  __builtin_amdgcn_global_load_lds((const __attribute__((address_space(1))) void*)g,
                                   (__attribute__((address_space(3))) void*)l, 16, 0, 0);
}

#define MFMA_BF16(a, b, c) __builtin_amdgcn_mfma_f32_16x16x32_bf16((a), (b), (c), 0, 0, 0)
#define EXP2(x) __builtin_amdgcn_exp2f(x)

// ---------------- LayerNorm (fp32 in -> bf16 out) ----------------
__global__ __launch_bounds__(256) void ln_kernel(const float* __restrict__ x,
                                                 const float* __restrict__ g,
                                                 const float* __restrict__ be,
                                                 u16* __restrict__ out) {
  __shared__ float red[10];
  int row = blockIdx.x;
  int t = threadIdx.x;
  const float* xr = x + (size_t)row * D_MODEL;
  float4 xv = ((const float4*)xr)[t];
  float s  = xv.x + xv.y + xv.z + xv.w;
  float s2 = xv.x*xv.x + xv.y*xv.y + xv.z*xv.z + xv.w*xv.w;
  for (int d = 32; d > 0; d >>= 1) { s += __shfl_down(s, d); s2 += __shfl_down(s2, d); }
  int wid = t >> 6;
  if ((t & 63) == 0) { red[wid*2] = s; red[wid*2+1] = s2; }
  __syncthreads();
  if (t == 0) {
    float a = 0.f, b2 = 0.f;
    for (int i = 0; i < 4; ++i) { a += red[i*2]; b2 += red[i*2+1]; }
    red[8] = a; red[9] = b2;
  }
  __syncthreads();
  float mu  = red[8] * (1.0f / D_MODEL);
  float var = red[9] * (1.0f / D_MODEL) - mu*mu;
  float rstd = rsqrtf(var + 1e-12f);
  float4 gv = ((const float4*)g)[t];
  float4 bv = ((const float4*)be)[t];
  unsigned long long o =
      (unsigned long long)f2bf((xv.x - mu) * rstd * gv.x + bv.x)
    | ((unsigned long long)f2bf((xv.y - mu) * rstd * gv.y + bv.y) << 16)
    | ((unsigned long long)f2bf((xv.z - mu) * rstd * gv.z + bv.z) << 32)
    | ((unsigned long long)f2bf((xv.w - mu) * rstd * gv.w + bv.w) << 48);
  ((unsigned long long*)out)[(size_t)row * (D_MODEL/4) + t] = o;
}

// ---------------- Weight transpose fp32 [K,N] -> bf16 [N,K] ----------------
__global__ __launch_bounds__(256) void wt_kernel(const float* __restrict__ W,
                                                 u16* __restrict__ Wt, int K, int N) {
  __shared__ float tile[32][33];
  int n0 = blockIdx.x * 32, k0 = blockIdx.y * 32;
  int tx = threadIdx.x & 31, ty = threadIdx.x >> 5;   // ty: 0..7
  #pragma unroll
  for (int i = 0; i < 4; ++i) {
    int k = ty + i*8;
    tile[k][tx] = W[(size_t)(k0 + k) * N + n0 + tx];
  }
  __syncthreads();
  #pragma unroll
  for (int i = 0; i < 4; ++i) {
    int n = ty + i*8;
    Wt[(size_t)(n0 + n) * K + k0 + tx] = f2bf(tile[tx][n]);
  }
}

// ---------------- V transpose: [b,key,h,d] bf16 -> [b,h,d,key] bf16 --------
__global__ __launch_bounds__(256) void vtrans_kernel(const u16* __restrict__ vb,
                                                     u16* __restrict__ vt) {
  __shared__ __align__(16) u16 tile[64][80];
  int kb = blockIdx.x * 64;       // key block
  int bh = blockIdx.y;            // b*16+h
  int b = bh >> 4, h = bh & 15;
  int t = threadIdx.x;
  int key = t >> 2, dq = (t & 3) * 16;
  const u16* src = vb + (size_t)b*SEQ*D_MODEL + (size_t)(kb+key)*D_MODEL + h*HDIM + dq;
  *(bf16x8*)&tile[key][dq]     = *(const bf16x8*)(src);
  *(bf16x8*)&tile[key][dq + 8] = *(const bf16x8*)(src + 8);
  __syncthreads();
  int w = t >> 6, lane = t & 63;
  int kq = w * 16;
  u16 vals[16];
  #pragma unroll
  for (int e = 0; e < 16; ++e) vals[e] = tile[kq + e][lane];
  u16* dst = vt + (size_t)bh * HDIM * SEQ + (size_t)lane * SEQ + kb + kq;
  *(bf16x8*)dst       = *(const bf16x8*)&vals[0];
  *(bf16x8*)(dst + 8) = *(const bf16x8*)&vals[8];
}

// ---------------- GEMM 128x256, BK=64, tri-buffered, pipelined frags -------
__device__ __forceinline__ float gelu_f(float v) {
  return 0.5f * v * (1.0f + erff(v * 0.70710678118654752f));
}

template<int EPI>
__global__ __launch_bounds__(512, 2) void gemm256(const u16* __restrict__ A,
                                                  const u16* __restrict__ Bt,
                                                  const float* __restrict__ bias,
                                                  const float* __restrict__ resid,
                                                  void* __restrict__ outp,
                                                  int M, int N, int K,
                                                  const float* __restrict__ bias2,
                                                  const float* __restrict__ bias3,
                                                  void* __restrict__ out2,
                                                  void* __restrict__ out3) {
  __shared__ __align__(16) u16 sA[3][128*64];   // 48 KiB
  __shared__ __align__(16) u16 sB[3][256*64];   // 96 KiB
  const int tid = threadIdx.x;
  const int lane = tid & 63, w = tid >> 6;
  const int r = lane & 15, kg = lane >> 4, r7 = r & 7;
  const int wr = w >> 2, wc = w & 3;

  // XCD-aware bijective swizzle (all launches have nwg % 8 == 0)
  const int gx = gridDim.x;
  const int nwg = gx * gridDim.y;
  const int orig = blockIdx.y * gx + blockIdx.x;
  const int lid = (orig & 7) * (nwg >> 3) + (orig >> 3);
  const int bm = lid / gx, bn = lid % gx;

  const int NT = K >> 6;

  size_t offA[2], offB[4];
  #pragma unroll
  for (int u = 0; u < 2; ++u) {
    int slot = u*512 + tid;
    int row = slot >> 3, g = slot & 7;
    offA[u] = (size_t)(bm*128 + row) * K + ((g ^ (row & 7)) * 8);
  }
  #pragma unroll
  for (int u = 0; u < 4; ++u) {
    int slot = u*512 + tid;
    int row = slot >> 3, g = slot & 7;
    offB[u] = (size_t)(bn*256 + row) * K + ((g ^ (row & 7)) * 8);
  }

  f32x4 acc[4][4];
  #pragma unroll
  for (int m = 0; m < 4; ++m)
    #pragma unroll
    for (int n = 0; n < 4; ++n) acc[m][n] = f32x4{0.f, 0.f, 0.f, 0.f};

  // per-section routing for EPI 3 (wave-uniform: bn 0-3 q, 4-7 k, 8-11 v)
  const float* bsel = bias;
  u16* osel = (u16*)outp;
  int bnl = bn;
  float qscale = 1.0f;
  if (EPI == 3) {
    int sec = bn >> 2;
    bsel = (sec == 0) ? bias : (sec == 1 ? bias2 : bias3);
    osel = (u16*)((sec == 0) ? outp : (sec == 1 ? out2 : out3));
    if (sec == 0) qscale = SCQ;
    bnl = bn & 3;
  }
  float bv4[4];
  #pragma unroll
  for (int n = 0; n < 4; ++n) bv4[n] = bsel[bnl*256 + wc*64 + n*16 + r];

  auto load_frags = [&](bf16x8 (&aa)[4], bf16x8 (&bb)[4], int bbuf, int sl) {
    #pragma unroll
    for (int m = 0; m < 4; ++m)
      aa[m] = *(const bf16x8*)&sA[bbuf][(wr*64 + m*16 + r)*64 + (((sl*4 + kg) ^ r7) * 8)];
    #pragma unroll
    for (int n = 0; n < 4; ++n)
      bb[n] = *(const bf16x8*)&sB[bbuf][(wc*64 + n*16 + r)*64 + (((sl*4 + kg) ^ r7) * 8)];
  };
  auto mfma16 = [&](bf16x8 (&aa)[4], bf16x8 (&bb)[4]) {
    __builtin_amdgcn_s_setprio(1);
    #pragma unroll
    for (int m = 0; m < 4; ++m)
      #pragma unroll
      for (int n = 0; n < 4; ++n)
        acc[m][n] = MFMA_BF16(aa[m], bb[n], acc[m][n]);
    __builtin_amdgcn_s_setprio(0);
  };

  // ---- prologue: stage K-tiles 0 and 1 ----
  #pragma unroll
  for (int u = 0; u < 2; ++u) gl2lds16(A  + offA[u],      &sA[0][(u*512+tid)*8]);
  #pragma unroll
  for (int u = 0; u < 4; ++u) gl2lds16(Bt + offB[u],      &sB[0][(u*512+tid)*8]);
  #pragma unroll
  for (int u = 0; u < 2; ++u) gl2lds16(A  + offA[u] + 64, &sA[1][(u*512+tid)*8]);
  #pragma unroll
  for (int u = 0; u < 4; ++u) gl2lds16(Bt + offB[u] + 64, &sB[1][(u*512+tid)*8]);
  asm volatile("s_waitcnt vmcnt(6)" ::: "memory");
  __builtin_amdgcn_s_barrier();

  bf16x8 a0[4], b0[4], a1[4], b1[4];
  load_frags(a0, b0, 0, 0);

  int buf = 0;
  for (int t = 0; t < NT - 1; ++t) {
    int nb = buf + 2; if (nb >= 3) nb -= 3;
    const bool pre = (t + 2 < NT);
    const size_t koff = (size_t)(t + 2) * 64;

    load_frags(a1, b1, buf, 1);          // slice-1 reads (covered by MFMA slice-0)
    if (pre) {
      gl2lds16(A  + offA[0] + koff, &sA[nb][(0*512+tid)*8]);
      gl2lds16(A  + offA[1] + koff, &sA[nb][(1*512+tid)*8]);
      gl2lds16(Bt + offB[0] + koff, &sB[nb][(0*512+tid)*8]);
      gl2lds16(Bt + offB[1] + koff, &sB[nb][(1*512+tid)*8]);
      gl2lds16(Bt + offB[2] + koff, &sB[nb][(2*512+tid)*8]);
      gl2lds16(Bt + offB[3] + koff, &sB[nb][(3*512+tid)*8]);
    }
    mfma16(a0, b0);                      // slice-0 MFMA
    asm volatile("s_waitcnt lgkmcnt(0)" ::: "memory");
    __builtin_amdgcn_sched_barrier(0);
    if (pre) asm volatile("s_waitcnt vmcnt(6)" ::: "memory");
    else     asm volatile("s_waitcnt vmcnt(0)" ::: "memory");
    __builtin_amdgcn_s_barrier();

    int bnext = buf + 1; if (bnext >= 3) bnext -= 3;
    load_frags(a0, b0, bnext, 0);        // next tile slice-0 (covered by MFMA slice-1)
    mfma16(a1, b1);                      // slice-1 MFMA
    buf = bnext;
  }
  // tail: last tile's slice 1
  load_frags(a1, b1, buf, 1);
  mfma16(a0, b0);
  mfma16(a1, b1);

  // ---- epilogue ----
  const int orow = bm*128 + wr*64;
  const int ocol = (EPI == 3 ? bnl : bn)*256 + wc*64;
  const int ostride = (EPI == 3) ? 1024 : N;
  #pragma unroll
  for (int m = 0; m < 4; ++m) {
    #pragma unroll
    for (int n = 0; n < 4; ++n) {
      #pragma unroll
      for (int j = 0; j < 4; ++j) {
        int rr = orow + m*16 + kg*4 + j;
        int cc = ocol + n*16 + r;
        size_t idx = (size_t)rr * ostride + cc;
        float v = acc[m][n][j] + bv4[n];
        if (EPI == 0)       ((u16*)outp)[idx]   = f2bf(v);
        else if (EPI == 1)  ((float*)outp)[idx] = resid[idx] + v;
        else if (EPI == 2)  ((u16*)outp)[idx]   = f2bf(gelu_f(v));
        else                osel[idx]           = f2bf(v * qscale);
      }
    }
  }
}

// ---------------- Flash attention: 4 waves/block, QBLK=16/wave, KVBLK=64 ---
// Steady-state K-loop has ZERO VMEM ops other than the counted gl2lds
// prefetch: mask handling hoisted to a per-block 32-bit tile bitmap
// (prologue), row-sums computed by 2 extra MFMAs against an all-ones
// B-fragment (exact, on the matrix pipe).
__global__ __launch_bounds__(256) void attn_kernel(const u16* __restrict__ qb,
                                                   const u16* __restrict__ kb,
                                                   const u16* __restrict__ vt,
                                                   const int* __restrict__ mask,
                                                   u16* __restrict__ ob) {
  __shared__ __align__(16) u16 sK[2][64*64];
  __shared__ __align__(16) u16 sV[2][64*64];
  __shared__ __align__(16) bf16_t sP[4][16*64];
  __shared__ unsigned char sOkPart[256];
  __shared__ unsigned sTileOk;
  const float THR2 = 11.541560327111708f;    // 8 * log2(e)
  int tid = threadIdx.x;
  int lane = tid & 63, w = tid >> 6;
  int r = lane & 15, kg = lane >> 4;
  int r7 = r & 7;
  int qt = blockIdx.x;
  int bh = blockIdx.y;
  int b = bh >> 4, h = bh & 15;
  size_t qkbase = (size_t)b * SEQ * D_MODEL + (size_t)h * HDIM;
  const u16* vtb = vt + (size_t)bh * HDIM * SEQ;
  const int* mrow = mask + b * SEQ;

  // ---- prologue: per-tile "fully unmasked" bitmap (32 tiles of 64 keys) ----
  {
    int ok = 1;
    #pragma unroll
    for (int e = 0; e < 8; ++e) ok &= (mrow[tid*8 + e] != 0);
    sOkPart[tid] = (unsigned char)ok;
  }
  __syncthreads();
  if (w == 0) {
    int a = 0;
    if (lane < 32) {
      a = 1;
      #pragma unroll
      for (int e = 0; e < 8; ++e) a &= sOkPart[lane*8 + e];
    }
    unsigned long long bits = __ballot(a != 0);
    if (lane == 0) sTileOk = (unsigned)(bits & 0xffffffffu);
  }
  __syncthreads();
  const unsigned tileOkBits = sTileOk;

  const u16* qrow = qb + qkbase + (size_t)(qt*64 + w*16 + r) * D_MODEL + kg*8;
  bf16x8 qf[2];
  qf[0] = *(const bf16x8*)(qrow);
  qf[1] = *(const bf16x8*)(qrow + 32);

  bf16x8 ones;
  {
    bf16_t one = (bf16_t)1.0f;
    #pragma unroll
    for (int e = 0; e < 8; ++e) ones[e] = one;
  }

  f32x4 oacc[4];
  #pragma unroll
  for (int n = 0; n < 4; ++n) oacc[n] = f32x4{0.f, 0.f, 0.f, 0.f};
  f32x4 oaccS = f32x4{0.f, 0.f, 0.f, 0.f};       // row sums (denominator)
  float m_run[4] = {-1e30f, -1e30f, -1e30f, -1e30f};

  // staging pointers (strength-reduced): chunk c0 = w*64+lane, c1 = +256
  int ch0 = w*64 + lane, ch1 = ch0 + 256;
  int row0 = ch0 >> 3, col0 = ((ch0 & 7) ^ (row0 & 7)) * 8;
  int row1 = ch1 >> 3, col1 = ((ch1 & 7) ^ (row1 & 7)) * 8;
  const u16* kp0 = kb + qkbase + (size_t)row0 * D_MODEL + col0;
  const u16* kp1 = kb + qkbase + (size_t)row1 * D_MODEL + col1;
  const u16* vp0 = vtb + (size_t)row0 * SEQ + col0;
  const u16* vp1 = vtb + (size_t)row1 * SEQ + col1;

  const int NT = SEQ / 64;

  // prologue stage tile 0
  gl2lds16(kp0, &sK[0][ch0*8]);
  gl2lds16(kp1, &sK[0][ch1*8]);
  gl2lds16(vp0, &sV[0][ch0*8]);
  gl2lds16(vp1, &sV[0][ch1*8]);
  kp0 += 64*D_MODEL; kp1 += 64*D_MODEL; vp0 += 64; vp1 += 64;

  #pragma unroll 2
  for (int kt = 0; kt < NT; ++kt) {
    int cur = kt & 1;
    int key0 = kt * 64;
    if (kt + 1 < NT) {
      gl2lds16(kp0, &sK[cur^1][ch0*8]);
      gl2lds16(kp1, &sK[cur^1][ch1*8]);
      gl2lds16(vp0, &sV[cur^1][ch0*8]);
      gl2lds16(vp1, &sV[cur^1][ch1*8]);
      kp0 += 64*D_MODEL; kp1 += 64*D_MODEL; vp0 += 64; vp1 += 64;
      asm volatile("s_waitcnt vmcnt(4)" ::: "memory");
    } else {
      asm volatile("s_waitcnt vmcnt(0)" ::: "memory");
    }
    __builtin_amdgcn_s_barrier();

    const u16* Kt = sK[cur];
    const u16* Vt = sV[cur];

    // ---- QK^T (scores already in exp2 domain via pre-scaled Q) ----
    f32x4 s[4];
    #pragma unroll
    for (int n = 0; n < 4; ++n) s[n] = f32x4{0.f, 0.f, 0.f, 0.f};
    #pragma unroll
    for (int c = 0; c < 2; ++c) {
      #pragma unroll
      for (int n = 0; n < 4; ++n) {
        bf16x8 kf = *(const bf16x8*)&Kt[(n*16 + r)*64 + (((c*4 + kg) ^ r7) * 8)];
        s[n] = MFMA_BF16(qf[c], kf, s[n]);
      }
    }

    // ---- mask slow path (rare; block-uniform branch, zero VMEM otherwise) --
    if (!((tileOkBits >> kt) & 1u)) {
      int mk[4];
      #pragma unroll
      for (int n = 0; n < 4; ++n) mk[n] = mrow[key0 + n*16 + r];
      #pragma unroll
      for (int n = 0; n < 4; ++n)
        #pragma unroll
        for (int j = 0; j < 4; ++j)
          s[n][j] = mk[n] ? s[n][j] : -1e9f;
    }
    float tm[4];
    #pragma unroll
    for (int n = 0; n < 4; ++n)
      #pragma unroll
      for (int j = 0; j < 4; ++j)
        tm[j] = (n == 0) ? s[n][j] : fmaxf(tm[j], s[n][j]);

    // ---- defer-max rescale (rare) ----
    bool grow = (tm[0] > m_run[0] + THR2) | (tm[1] > m_run[1] + THR2) |
                (tm[2] > m_run[2] + THR2) | (tm[3] > m_run[3] + THR2);
    if (__any(grow)) {
      #pragma unroll
      for (int d = 1; d < 16; d <<= 1) {
        #pragma unroll
        for (int j = 0; j < 4; ++j) tm[j] = fmaxf(tm[j], __shfl_xor(tm[j], d));
      }
      #pragma unroll
      for (int j = 0; j < 4; ++j) {
        float mn = fmaxf(m_run[j], tm[j]);
        float al = EXP2(m_run[j] - mn);
        m_run[j] = mn;
        oaccS[j] *= al;
        oacc[0][j] *= al; oacc[1][j] *= al; oacc[2][j] *= al; oacc[3][j] *= al;
      }
    }
    // ---- P = exp2(s - m); per-wave LDS (swizzled) ----
    bf16_t* pw = sP[w];
    #pragma unroll
    for (int n = 0; n < 4; ++n) {
      int cg = n*2 + (r >> 3);
      #pragma unroll
      for (int j = 0; j < 4; ++j) {
        float p = EXP2(s[n][j] - m_run[j]);
        int row = kg*4 + j;
        pw[row*64 + ((cg ^ (row & 7)) * 8) + r7] = (bf16_t)p;
      }
    }
    bf16x8 pa[2];
    #pragma unroll
    for (int c = 0; c < 2; ++c)
      pa[c] = *(const bf16x8*)&sP[w][r*64 + (((c*4 + kg) ^ r7) * 8)];
    #pragma unroll
    for (int c = 0; c < 2; ++c) {
      #pragma unroll
      for (int n = 0; n < 4; ++n) {
        bf16x8 vf = *(const bf16x8*)&Vt[(n*16 + r)*64 + (((c*4 + kg) ^ r7) * 8)];
        oacc[n] = MFMA_BF16(pa[c], vf, oacc[n]);
      }
      oaccS = MFMA_BF16(pa[c], ones, oaccS);   // exact row sums on MFMA pipe
    }
    __builtin_amdgcn_s_barrier();
  }

  float rcp[4];
  #pragma unroll
  for (int j = 0; j < 4; ++j) rcp[j] = 1.0f / oaccS[j];
  #pragma unroll
  for (int n = 0; n < 4; ++n) {
    #pragma unroll
    for (int j = 0; j < 4; ++j) {
      int q = qt*64 + w*16 + kg*4 + j;
      int d = h*HDIM + n*16 + r;
      ob[(size_t)(b*SEQ + q) * D_MODEL + d] = f2bf(oacc[n][j] * rcp[j]);
    }
  }
}

// ---------------- launch ----------------
extern "C" void kernel_launch(void* const* d_in, const int* in_sizes, int n_in,
                              void* d_out, int out_size, void* d_ws, size_t ws_size,
                              hipStream_t stream) {
  const float* x   = (const float*)d_in[0];
  const int*  mask = (const int*)d_in[1];
  const float* Wq = (const float*)d_in[2];  const float* bq = (const float*)d_in[3];
  const float* Wk = (const float*)d_in[4];  const float* bk = (const float*)d_in[5];
  const float* Wv = (const float*)d_in[6];  const float* bv = (const float*)d_in[7];
  const float* Wo = (const float*)d_in[8];  const float* bo = (const float*)d_in[9];
  const float* W1 = (const float*)d_in[10]; const float* b1 = (const float*)d_in[11];
  const float* W2 = (const float*)d_in[12]; const float* b2 = (const float*)d_in[13];
  const float* g1 = (const float*)d_in[14]; const float* be1 = (const float*)d_in[15];
  const float* g2 = (const float*)d_in[16]; const float* be2 = (const float*)d_in[17];

  const size_t MB = 1u << 20;
  char* ws = (char*)d_ws;
  u16*  hln  = (u16*)(ws);              // 16MB  (LN1 out; later reused: vt, then LN2 out)
  u16*  vt   = (u16*)(ws);              // 16MB  V^T [b,h,d,key] — overwrites hln after QKV
  u16*  qb   = (u16*)(ws + 16*MB);      // 16MB
  u16*  kb   = (u16*)(ws + 32*MB);      // 16MB
  u16*  vb   = (u16*)(ws + 48*MB);      // 16MB
  u16*  attn = (u16*)(ws + 64*MB);      // 16MB
  u16*  ff1  = (u16*)(ws + 16*MB);      // 64MB, reuses q/k/v/attn region
  float* x2  = (float*)(ws + 80*MB);    // 32MB
  u16*  WqkvT= (u16*)(ws + 112*MB);     // 6MB contiguous: [3072][1024] (q|k|v)
  u16*  WqT  = WqkvT;
  u16*  WkT  = (u16*)(ws + 114*MB);
  u16*  WvT  = (u16*)(ws + 116*MB);
  u16*  WoT  = (u16*)(ws + 118*MB);
  u16*  W1T  = (u16*)(ws + 120*MB);     // [4096,1024] 8MB
  u16*  W2T  = (u16*)(ws + 128*MB);     // [1024,4096] 8MB

  dim3 tb(256);
  wt_kernel<<<dim3(1024/32, 1024/32), tb, 0, stream>>>(Wq, WqT, 1024, 1024);
  wt_kernel<<<dim3(1024/32, 1024/32), tb, 0, stream>>>(Wk, WkT, 1024, 1024);
  wt_kernel<<<dim3(1024/32, 1024/32), tb, 0, stream>>>(Wv, WvT, 1024, 1024);
  wt_kernel<<<dim3(1024/32, 1024/32), tb, 0, stream>>>(Wo, WoT, 1024, 1024);
  wt_kernel<<<dim3(4096/32, 1024/32), tb, 0, stream>>>(W1, W1T, 1024, 4096);
  wt_kernel<<<dim3(1024/32, 4096/32), tb, 0, stream>>>(W2, W2T, 4096, 1024);

  ln_kernel<<<ROWS, tb, 0, stream>>>(x, g1, be1, hln);

  dim3 gb(512);
  // fused QKV: one GEMM over [3072][1024] weights, routed epilogue (q pre-scaled)
  gemm256<3><<<dim3(3072/256, ROWS/128), gb, 0, stream>>>(hln, WqkvT, bq, nullptr, qb,
                                                          ROWS, 3072, 1024,
                                                          bk, bv, kb, vb);

  vtrans_kernel<<<dim3(SEQ/64, BATCH*NHEAD), tb, 0, stream>>>(vb, vt);

  attn_kernel<<<dim3(SEQ/64, BATCH*NHEAD), tb, 0, stream>>>(qb, kb, vt, mask, attn);

  gemm256<1><<<dim3(1024/256, ROWS/128), gb, 0, stream>>>(attn, WoT, bo, x, x2,
                                                          ROWS, 1024, 1024,
                                                          nullptr, nullptr, nullptr, nullptr);

  ln_kernel<<<ROWS, tb, 0, stream>>>(x2, g2, be2, hln);

  gemm256<2><<<dim3(4096/256, ROWS/128), gb, 0, stream>>>(hln, W1T, b1, nullptr, ff1,
                                                          ROWS, 4096, 1024,
                                                          nullptr, nullptr, nullptr, nullptr);

  gemm256<1><<<dim3(1024/256, ROWS/128), gb, 0, stream>>>(ff1, W2T, b2, x2, (float*)d_out,
                                                          ROWS, 1024, 4096,
                                                          nullptr, nullptr, nullptr, nullptr);
}

// Round 8
// 387.842 us; speedup vs baseline: 1.3106x; 1.1049x over previous
//
#include <hip/hip_runtime.h>
#include <stdint.h>

#define D_MODEL 1024
#define NHEAD   16
#define HDIM    64
#define FFDIM   4096
#define BATCH   4
#define SEQ     2048
#define ROWS    (BATCH*SEQ)   // 8192

typedef unsigned short u16;
typedef __bf16 bf16_t;
typedef bf16_t bf16x8 __attribute__((ext_vector_type(8)));
typedef float  f32x4  __attribute__((ext_vector_type(4)));
typedef float  f32x16 __attribute__((ext_vector_type(16)));

#define SCQ 0.18033688011112042f   // 0.125 * log2(e) — folded into Q at QKV epilogue

__device__ __forceinline__ u16 f2bf(float f) {
  union { float f; unsigned u; } v; v.f = f;
  unsigned r = v.u + 0x7fffu + ((v.u >> 16) & 1u);
  return (u16)(r >> 16);
}

__device__ __forceinline__ void gl2lds16(const void* g, void* l) {
  __builtin_amdgcn_global_load_lds((const __attribute__((address_space(1))) void*)g,
                                   (__attribute__((address_space(3))) void*)l, 16, 0, 0);
}

#define MFMA_BF16(a, b, c) __builtin_amdgcn_mfma_f32_16x16x32_bf16((a), (b), (c), 0, 0, 0)
#define MFMA32(a, b, c)    __builtin_amdgcn_mfma_f32_32x32x16_bf16((a), (b), (c), 0, 0, 0)
#define EXP2(x) __builtin_amdgcn_exp2f(x)

__device__ __forceinline__ bf16x8 mk8(unsigned a, unsigned b, unsigned c, unsigned d) {
  union { unsigned u[4]; bf16x8 v; } t;
  t.u[0] = a; t.u[1] = b; t.u[2] = c; t.u[3] = d;
  return t.v;
}

// ---------------- LayerNorm (fp32 in -> bf16 out) ----------------
__global__ __launch_bounds__(256) void ln_kernel(const float* __restrict__ x,
                                                 const float* __restrict__ g,
                                                 const float* __restrict__ be,
                                                 u16* __restrict__ out) {
  __shared__ float red[10];
  int row = blockIdx.x;
  int t = threadIdx.x;
  const float* xr = x + (size_t)row * D_MODEL;
  float4 xv = ((const float4*)xr)[t];
  float s  = xv.x + xv.y + xv.z + xv.w;
  float s2 = xv.x*xv.x + xv.y*xv.y + xv.z*xv.z + xv.w*xv.w;
  for (int d = 32; d > 0; d >>= 1) { s += __shfl_down(s, d); s2 += __shfl_down(s2, d); }
  int wid = t >> 6;
  if ((t & 63) == 0) { red[wid*2] = s; red[wid*2+1] = s2; }
  __syncthreads();
  if (t == 0) {
    float a = 0.f, b2 = 0.f;
    for (int i = 0; i < 4; ++i) { a += red[i*2]; b2 += red[i*2+1]; }
    red[8] = a; red[9] = b2;
  }
  __syncthreads();
  float mu  = red[8] * (1.0f / D_MODEL);
  float var = red[9] * (1.0f / D_MODEL) - mu*mu;
  float rstd = rsqrtf(var + 1e-12f);
  float4 gv = ((const float4*)g)[t];
  float4 bv = ((const float4*)be)[t];
  unsigned long long o =
      (unsigned long long)f2bf((xv.x - mu) * rstd * gv.x + bv.x)
    | ((unsigned long long)f2bf((xv.y - mu) * rstd * gv.y + bv.y) << 16)
    | ((unsigned long long)f2bf((xv.z - mu) * rstd * gv.z + bv.z) << 32)
    | ((unsigned long long)f2bf((xv.w - mu) * rstd * gv.w + bv.w) << 48);
  ((unsigned long long*)out)[(size_t)row * (D_MODEL/4) + t] = o;
}

// ---------------- Weight transpose fp32 [K,N] -> bf16 [N,K] ----------------
__global__ __launch_bounds__(256) void wt_kernel(const float* __restrict__ W,
                                                 u16* __restrict__ Wt, int K, int N) {
  __shared__ float tile[32][33];
  int n0 = blockIdx.x * 32, k0 = blockIdx.y * 32;
  int tx = threadIdx.x & 31, ty = threadIdx.x >> 5;   // ty: 0..7
  #pragma unroll
  for (int i = 0; i < 4; ++i) {
    int k = ty + i*8;
    tile[k][tx] = W[(size_t)(k0 + k) * N + n0 + tx];
  }
  __syncthreads();
  #pragma unroll
  for (int i = 0; i < 4; ++i) {
    int n = ty + i*8;
    Wt[(size_t)(n0 + n) * K + k0 + tx] = f2bf(tile[tx][n]);
  }
}

// ---------------- V transpose: [b,key,h,d] bf16 -> [b,h,d,key] bf16 --------
__global__ __launch_bounds__(256) void vtrans_kernel(const u16* __restrict__ vb,
                                                     u16* __restrict__ vt) {
  __shared__ __align__(16) u16 tile[64][80];
  int kb = blockIdx.x * 64;       // key block
  int bh = blockIdx.y;            // b*16+h
  int b = bh >> 4, h = bh & 15;
  int t = threadIdx.x;
  int key = t >> 2, dq = (t & 3) * 16;
  const u16* src = vb + (size_t)b*SEQ*D_MODEL + (size_t)(kb+key)*D_MODEL + h*HDIM + dq;
  *(bf16x8*)&tile[key][dq]     = *(const bf16x8*)(src);
  *(bf16x8*)&tile[key][dq + 8] = *(const bf16x8*)(src + 8);
  __syncthreads();
  int w = t >> 6, lane = t & 63;
  int kq = w * 16;
  u16 vals[16];
  #pragma unroll
  for (int e = 0; e < 16; ++e) vals[e] = tile[kq + e][lane];
  u16* dst = vt + (size_t)bh * HDIM * SEQ + (size_t)lane * SEQ + kb + kq;
  *(bf16x8*)dst       = *(const bf16x8*)&vals[0];
  *(bf16x8*)(dst + 8) = *(const bf16x8*)&vals[8];
}

// ---------------- GEMM 128x256, BK=64, tri-buffered, pipelined frags -------
__device__ __forceinline__ float gelu_f(float v) {
  return 0.5f * v * (1.0f + erff(v * 0.70710678118654752f));
}

template<int EPI>
__global__ __launch_bounds__(512, 2) void gemm256(const u16* __restrict__ A,
                                                  const u16* __restrict__ Bt,
                                                  const float* __restrict__ bias,
                                                  const float* __restrict__ resid,
                                                  void* __restrict__ outp,
                                                  int M, int N, int K,
                                                  const float* __restrict__ bias2,
                                                  const float* __restrict__ bias3,
                                                  void* __restrict__ out2,
                                                  void* __restrict__ out3) {
  __shared__ __align__(16) u16 sA[3][128*64];   // 48 KiB
  __shared__ __align__(16) u16 sB[3][256*64];   // 96 KiB
  const int tid = threadIdx.x;
  const int lane = tid & 63, w = tid >> 6;
  const int r = lane & 15, kg = lane >> 4, r7 = r & 7;
  const int wr = w >> 2, wc = w & 3;

  // XCD-aware bijective swizzle (all launches have nwg % 8 == 0)
  const int gx = gridDim.x;
  const int nwg = gx * gridDim.y;
  const int orig = blockIdx.y * gx + blockIdx.x;
  const int lid = (orig & 7) * (nwg >> 3) + (orig >> 3);
  const int bm = lid / gx, bn = lid % gx;

  const int NT = K >> 6;

  size_t offA[2], offB[4];
  #pragma unroll
  for (int u = 0; u < 2; ++u) {
    int slot = u*512 + tid;
    int row = slot >> 3, g = slot & 7;
    offA[u] = (size_t)(bm*128 + row) * K + ((g ^ (row & 7)) * 8);
  }
  #pragma unroll
  for (int u = 0; u < 4; ++u) {
    int slot = u*512 + tid;
    int row = slot >> 3, g = slot & 7;
    offB[u] = (size_t)(bn*256 + row) * K + ((g ^ (row & 7)) * 8);
  }

  f32x4 acc[4][4];
  #pragma unroll
  for (int m = 0; m < 4; ++m)
    #pragma unroll
    for (int n = 0; n < 4; ++n) acc[m][n] = f32x4{0.f, 0.f, 0.f, 0.f};

  // per-section routing for EPI 3 (wave-uniform: bn 0-3 q, 4-7 k, 8-11 v)
  const float* bsel = bias;
  u16* osel = (u16*)outp;
  int bnl = bn;
  float qscale = 1.0f;
  if (EPI == 3) {
    int sec = bn >> 2;
    bsel = (sec == 0) ? bias : (sec == 1 ? bias2 : bias3);
    osel = (u16*)((sec == 0) ? outp : (sec == 1 ? out2 : out3));
    if (sec == 0) qscale = SCQ;
    bnl = bn & 3;
  }
  float bv4[4];
  #pragma unroll
  for (int n = 0; n < 4; ++n) bv4[n] = bsel[bnl*256 + wc*64 + n*16 + r];

  auto load_frags = [&](bf16x8 (&aa)[4], bf16x8 (&bb)[4], int bbuf, int sl) {
    #pragma unroll
    for (int m = 0; m < 4; ++m)
      aa[m] = *(const bf16x8*)&sA[bbuf][(wr*64 + m*16 + r)*64 + (((sl*4 + kg) ^ r7) * 8)];
    #pragma unroll
    for (int n = 0; n < 4; ++n)
      bb[n] = *(const bf16x8*)&sB[bbuf][(wc*64 + n*16 + r)*64 + (((sl*4 + kg) ^ r7) * 8)];
  };
  auto mfma16 = [&](bf16x8 (&aa)[4], bf16x8 (&bb)[4]) {
    __builtin_amdgcn_s_setprio(1);
    #pragma unroll
    for (int m = 0; m < 4; ++m)
      #pragma unroll
      for (int n = 0; n < 4; ++n)
        acc[m][n] = MFMA_BF16(aa[m], bb[n], acc[m][n]);
    __builtin_amdgcn_s_setprio(0);
  };

  // ---- prologue: stage K-tiles 0 and 1 ----
  #pragma unroll
  for (int u = 0; u < 2; ++u) gl2lds16(A  + offA[u],      &sA[0][(u*512+tid)*8]);
  #pragma unroll
  for (int u = 0; u < 4; ++u) gl2lds16(Bt + offB[u],      &sB[0][(u*512+tid)*8]);
  #pragma unroll
  for (int u = 0; u < 2; ++u) gl2lds16(A  + offA[u] + 64, &sA[1][(u*512+tid)*8]);
  #pragma unroll
  for (int u = 0; u < 4; ++u) gl2lds16(Bt + offB[u] + 64, &sB[1][(u*512+tid)*8]);
  asm volatile("s_waitcnt vmcnt(6)" ::: "memory");
  __builtin_amdgcn_s_barrier();

  bf16x8 a0[4], b0[4], a1[4], b1[4];
  load_frags(a0, b0, 0, 0);

  int buf = 0;
  for (int t = 0; t < NT - 1; ++t) {
    int nb = buf + 2; if (nb >= 3) nb -= 3;
    const bool pre = (t + 2 < NT);
    const size_t koff = (size_t)(t + 2) * 64;

    load_frags(a1, b1, buf, 1);          // slice-1 reads (covered by MFMA slice-0)
    if (pre) {
      gl2lds16(A  + offA[0] + koff, &sA[nb][(0*512+tid)*8]);
      gl2lds16(A  + offA[1] + koff, &sA[nb][(1*512+tid)*8]);
      gl2lds16(Bt + offB[0] + koff, &sB[nb][(0*512+tid)*8]);
      gl2lds16(Bt + offB[1] + koff, &sB[nb][(1*512+tid)*8]);
      gl2lds16(Bt + offB[2] + koff, &sB[nb][(2*512+tid)*8]);
      gl2lds16(Bt + offB[3] + koff, &sB[nb][(3*512+tid)*8]);
    }
    mfma16(a0, b0);                      // slice-0 MFMA
    asm volatile("s_waitcnt lgkmcnt(0)" ::: "memory");
    __builtin_amdgcn_sched_barrier(0);
    if (pre) asm volatile("s_waitcnt vmcnt(6)" ::: "memory");
    else     asm volatile("s_waitcnt vmcnt(0)" ::: "memory");
    __builtin_amdgcn_s_barrier();

    int bnext = buf + 1; if (bnext >= 3) bnext -= 3;
    load_frags(a0, b0, bnext, 0);        // next tile slice-0 (covered by MFMA slice-1)
    mfma16(a1, b1);                      // slice-1 MFMA
    buf = bnext;
  }
  // tail: last tile's slice 1
  load_frags(a1, b1, buf, 1);
  mfma16(a0, b0);
  mfma16(a1, b1);

  // ---- epilogue ----
  const int orow = bm*128 + wr*64;
  const int ocol = (EPI == 3 ? bnl : bn)*256 + wc*64;
  const int ostride = (EPI == 3) ? 1024 : N;
  #pragma unroll
  for (int m = 0; m < 4; ++m) {
    #pragma unroll
    for (int n = 0; n < 4; ++n) {
      #pragma unroll
      for (int j = 0; j < 4; ++j) {
        int rr = orow + m*16 + kg*4 + j;
        int cc = ocol + n*16 + r;
        size_t idx = (size_t)rr * ostride + cc;
        float v = acc[m][n][j] + bv4[n];
        if (EPI == 0)       ((u16*)outp)[idx]   = f2bf(v);
        else if (EPI == 1)  ((float*)outp)[idx] = resid[idx] + v;
        else if (EPI == 2)  ((u16*)outp)[idx]   = f2bf(gelu_f(v));
        else                osel[idx]           = f2bf(v * qscale);
      }
    }
  }
}

// ---------------- Flash attention: 4 waves, 32 q/wave, 32x32 MFMA ---------
// Swapped QK^T (mfma(K,Q)) => each lane owns one q-column; softmax fully
// in-register; P->A-frag via v_cvt_pk_bf16_f32 + v_permlane32_swap_b32
// (no P LDS). LDS = K/V double-buffer only (~33KB -> 4 blocks/CU; grid
// 1024 = all blocks resident, single round).
__global__ __launch_bounds__(256, 4) void attn_kernel(const u16* __restrict__ qb,
                                                      const u16* __restrict__ kb,
                                                      const u16* __restrict__ vt,
                                                      const int* __restrict__ mask,
                                                      u16* __restrict__ ob) {
  __shared__ __align__(16) u16 sK[2][64*64];   // 16 KiB
  __shared__ __align__(16) u16 sV[2][64*64];   // 16 KiB
  __shared__ float sAl[4][32];                 // per-wave alpha/rcp broadcast
  __shared__ unsigned char sOkPart[256];
  __shared__ unsigned sTileOk;
  const float THR2 = 11.541560327111708f;      // 8 * log2(e)
  int tid = threadIdx.x;
  int lane = tid & 63, w = tid >> 6;
  int l31 = lane & 31, hi = lane >> 5;
  int qt = blockIdx.x;            // 0..15, 128 q-rows per block
  int bh = blockIdx.y;
  int b = bh >> 4, h = bh & 15;
  size_t qkbase = (size_t)b * SEQ * D_MODEL + (size_t)h * HDIM;
  const u16* vtb = vt + (size_t)bh * HDIM * SEQ;
  const int* mrow = mask + b * SEQ;

  // ---- prologue: per-tile "fully unmasked" bitmap (32 tiles of 64 keys) ----
  {
    int ok = 1;
    #pragma unroll
    for (int e = 0; e < 8; ++e) ok &= (mrow[tid*8 + e] != 0);
    sOkPart[tid] = (unsigned char)ok;
  }
  __syncthreads();
  if (w == 0) {
    int a = 0;
    if (lane < 32) {
      a = 1;
      #pragma unroll
      for (int e = 0; e < 8; ++e) a &= sOkPart[lane*8 + e];
    }
    unsigned long long bits = __ballot(a != 0);
    if (lane == 0) sTileOk = (unsigned)(bits & 0xffffffffu);
  }
  __syncthreads();
  const unsigned tileOkBits = sTileOk;

  // Q fragments (B-operand): lane holds Q[q=l31][d = dstep*16 + hi*8 + e]
  const u16* qrow = qb + qkbase + (size_t)(qt*128 + w*32 + l31) * D_MODEL + hi*8;
  bf16x8 qf[4];
  #pragma unroll
  for (int dstep = 0; dstep < 4; ++dstep)
    qf[dstep] = *(const bf16x8*)(qrow + dstep*16);

  f32x16 oacc0, oacc1;           // O[q-rows][d = l31] and [d = 32+l31]
  #pragma unroll
  for (int e = 0; e < 16; ++e) { oacc0[e] = 0.f; oacc1[e] = 0.f; }
  float m_run = -1e30f;
  float lsum  = 0.f;

  // staging pointers: chunk c0 = w*64+lane, c1 = +256 (same as before)
  int ch0 = w*64 + lane, ch1 = ch0 + 256;
  int row0 = ch0 >> 3, col0 = ((ch0 & 7) ^ (row0 & 7)) * 8;
  int row1 = ch1 >> 3, col1 = ((ch1 & 7) ^ (row1 & 7)) * 8;
  const u16* kp0 = kb + qkbase + (size_t)row0 * D_MODEL + col0;
  const u16* kp1 = kb + qkbase + (size_t)row1 * D_MODEL + col1;
  const u16* vp0 = vtb + (size_t)row0 * SEQ + col0;
  const u16* vp1 = vtb + (size_t)row1 * SEQ + col1;

  const int NT = SEQ / 64;

  gl2lds16(kp0, &sK[0][ch0*8]);
  gl2lds16(kp1, &sK[0][ch1*8]);
  gl2lds16(vp0, &sV[0][ch0*8]);
  gl2lds16(vp1, &sV[0][ch1*8]);
  kp0 += 64*D_MODEL; kp1 += 64*D_MODEL; vp0 += 64; vp1 += 64;

  for (int kt = 0; kt < NT; ++kt) {
    int cur = kt & 1;
    int key0 = kt * 64;
    if (kt + 1 < NT) {
      gl2lds16(kp0, &sK[cur^1][ch0*8]);
      gl2lds16(kp1, &sK[cur^1][ch1*8]);
      gl2lds16(vp0, &sV[cur^1][ch0*8]);
      gl2lds16(vp1, &sV[cur^1][ch1*8]);
      kp0 += 64*D_MODEL; kp1 += 64*D_MODEL; vp0 += 64; vp1 += 64;
      asm volatile("s_waitcnt vmcnt(4)" ::: "memory");
    } else {
      asm volatile("s_waitcnt vmcnt(0)" ::: "memory");
    }
    __builtin_amdgcn_s_barrier();

    const u16* Kt = sK[cur];
    const u16* Vt = sV[cur];

    // ---- QK^T swapped: S[k][q], q = l31; s0 = keys 0..31, s1 = 32..63 ----
    f32x16 s0, s1;
    #pragma unroll
    for (int e = 0; e < 16; ++e) { s0[e] = 0.f; s1[e] = 0.f; }
    #pragma unroll
    for (int dstep = 0; dstep < 4; ++dstep) {
      int g = dstep*2 + hi;
      bf16x8 kf0 = *(const bf16x8*)&Kt[l31*64        + ((g ^ (l31 & 7)) * 8)];
      bf16x8 kf1 = *(const bf16x8*)&Kt[(32 + l31)*64 + ((g ^ ((32 + l31) & 7)) * 8)];
      s0 = MFMA32(kf0, qf[dstep], s0);
      s1 = MFMA32(kf1, qf[dstep], s1);
    }

    // ---- mask slow path (rare; block-uniform) ----
    if (!((tileOkBits >> kt) & 1u)) {
      #pragma unroll
      for (int reg = 0; reg < 16; ++reg) {
        int kr = (reg & 3) + 8*(reg >> 2) + 4*hi;
        if (!mrow[key0 + kr])      s0[reg] = -1e9f;
        if (!mrow[key0 + 32 + kr]) s1[reg] = -1e9f;
      }
    }

    // ---- per-q tile max (lane-local 31 fmax + one cross-half shfl) ----
    float tm = s0[0];
    #pragma unroll
    for (int e = 1; e < 16; ++e) tm = fmaxf(tm, s0[e]);
    #pragma unroll
    for (int e = 0; e < 16; ++e) tm = fmaxf(tm, s1[e]);
    tm = fmaxf(tm, __shfl_xor(tm, 32));

    // ---- defer-max rescale (rare) ----
    if (__any(tm > m_run + THR2)) {
      float mn = fmaxf(m_run, tm);
      float al = EXP2(m_run - mn);
      m_run = mn;
      lsum *= al;
      if (lane < 32) sAl[w][lane] = al;
      asm volatile("s_waitcnt lgkmcnt(0)" ::: "memory");
      #pragma unroll
      for (int reg = 0; reg < 16; ++reg) {
        float a2 = sAl[w][(reg & 3) + 8*(reg >> 2) + 4*hi];
        oacc0[reg] *= a2; oacc1[reg] *= a2;
      }
    }

    // ---- P = exp2(s - m), lane-local row-sum ----
    #pragma unroll
    for (int e = 0; e < 16; ++e) {
      s0[e] = EXP2(s0[e] - m_run); lsum += s0[e];
      s1[e] = EXP2(s1[e] - m_run); lsum += s1[e];
    }

    // ---- pack P to bf16 A-frags in-register (cvt_pk + permlane32_swap) ----
    unsigned wa, wb, wc, wd, we, wf, wg, wh;
#define CVTPK(dst, lo_, hi_) asm("v_cvt_pk_bf16_f32 %0, %1, %2" : "=v"(dst) : "v"(lo_), "v"(hi_))
    CVTPK(wa, s0[0],  s0[1]);  CVTPK(wb, s0[2],  s0[3]);
    CVTPK(wc, s0[4],  s0[5]);  CVTPK(wd, s0[6],  s0[7]);
    CVTPK(we, s0[8],  s0[9]);  CVTPK(wf, s0[10], s0[11]);
    CVTPK(wg, s0[12], s0[13]); CVTPK(wh, s0[14], s0[15]);
    asm volatile("v_permlane32_swap_b32 %0, %1" : "+v"(wc), "+v"(wa));
    asm volatile("v_permlane32_swap_b32 %0, %1" : "+v"(wd), "+v"(wb));
    asm volatile("v_permlane32_swap_b32 %0, %1" : "+v"(wg), "+v"(we));
    asm volatile("v_permlane32_swap_b32 %0, %1" : "+v"(wh), "+v"(wf));
    bf16x8 pa0 = mk8(wa, wb, wc, wd);   // keys 0..15
    bf16x8 pa1 = mk8(we, wf, wg, wh);   // keys 16..31
    CVTPK(wa, s1[0],  s1[1]);  CVTPK(wb, s1[2],  s1[3]);
    CVTPK(wc, s1[4],  s1[5]);  CVTPK(wd, s1[6],  s1[7]);
    CVTPK(we, s1[8],  s1[9]);  CVTPK(wf, s1[10], s1[11]);
    CVTPK(wg, s1[12], s1[13]); CVTPK(wh, s1[14], s1[15]);
    asm volatile("v_permlane32_swap_b32 %0, %1" : "+v"(wc), "+v"(wa));
    asm volatile("v_permlane32_swap_b32 %0, %1" : "+v"(wd), "+v"(wb));
    asm volatile("v_permlane32_swap_b32 %0, %1" : "+v"(wg), "+v"(we));
    asm volatile("v_permlane32_swap_b32 %0, %1" : "+v"(wh), "+v"(wf));
    bf16x8 pa2 = mk8(wa, wb, wc, wd);   // keys 32..47
    bf16x8 pa3 = mk8(we, wf, wg, wh);   // keys 48..63
#undef CVTPK

    // ---- PV: O[q][d] += P[q][k] V[k][d]; B-frag from vt rows (d-major) ----
    int r0 = l31, r1 = 32 + l31;
    #pragma unroll
    for (int kstep = 0; kstep < 4; ++kstep) {
      int g = kstep*2 + hi;
      bf16x8 vf0 = *(const bf16x8*)&Vt[r0*64 + ((g ^ (r0 & 7)) * 8)];
      bf16x8 vf1 = *(const bf16x8*)&Vt[r1*64 + ((g ^ (r1 & 7)) * 8)];
      bf16x8 pk = (kstep == 0) ? pa0 : (kstep == 1) ? pa1 : (kstep == 2) ? pa2 : pa3;
      oacc0 = MFMA32(pk, vf0, oacc0);
      oacc1 = MFMA32(pk, vf1, oacc1);
    }
    __builtin_amdgcn_s_barrier();
  }

  // ---- finalize: per-q 1/l broadcast, normalize, store ----
  float lsumT = lsum + __shfl_xor(lsum, 32);
  if (lane < 32) sAl[w][lane] = 1.0f / lsumT;
  asm volatile("s_waitcnt lgkmcnt(0)" ::: "memory");
  #pragma unroll
  for (int reg = 0; reg < 16; ++reg) {
    int qr = (reg & 3) + 8*(reg >> 2) + 4*hi;
    float rc = sAl[w][qr];
    int qg = qt*128 + w*32 + qr;
    size_t base2 = (size_t)(b*SEQ + qg) * D_MODEL + h*HDIM + l31;
    ob[base2]      = f2bf(oacc0[reg] * rc);
    ob[base2 + 32] = f2bf(oacc1[reg] * rc);
  }
}

// ---------------- launch ----------------
extern "C" void kernel_launch(void* const* d_in, const int* in_sizes, int n_in,
                              void* d_out, int out_size, void* d_ws, size_t ws_size,
                              hipStream_t stream) {
  const float* x   = (const float*)d_in[0];
  const int*  mask = (const int*)d_in[1];
  const float* Wq = (const float*)d_in[2];  const float* bq = (const float*)d_in[3];
  const float* Wk = (const float*)d_in[4];  const float* bk = (const float*)d_in[5];
  const float* Wv = (const float*)d_in[6];  const float* bv = (const float*)d_in[7];
  const float* Wo = (const float*)d_in[8];  const float* bo = (const float*)d_in[9];
  const float* W1 = (const float*)d_in[10]; const float* b1 = (const float*)d_in[11];
  const float* W2 = (const float*)d_in[12]; const float* b2 = (const float*)d_in[13];
  const float* g1 = (const float*)d_in[14]; const float* be1 = (const float*)d_in[15];
  const float* g2 = (const float*)d_in[16]; const float* be2 = (const float*)d_in[17];

  const size_t MB = 1u << 20;
  char* ws = (char*)d_ws;
  u16*  hln  = (u16*)(ws);              // 16MB  (LN1 out; later reused: vt, then LN2 out)
  u16*  vt   = (u16*)(ws);              // 16MB  V^T [b,h,d,key] — overwrites hln after QKV
  u16*  qb   = (u16*)(ws + 16*MB);      // 16MB
  u16*  kb   = (u16*)(ws + 32*MB);      // 16MB
  u16*  vb   = (u16*)(ws + 48*MB);      // 16MB
  u16*  attn = (u16*)(ws + 64*MB);      // 16MB
  u16*  ff1  = (u16*)(ws + 16*MB);      // 64MB, reuses q/k/v/attn region
  float* x2  = (float*)(ws + 80*MB);    // 32MB
  u16*  WqkvT= (u16*)(ws + 112*MB);     // 6MB contiguous: [3072][1024] (q|k|v)
  u16*  WqT  = WqkvT;
  u16*  WkT  = (u16*)(ws + 114*MB);
  u16*  WvT  = (u16*)(ws + 116*MB);
  u16*  WoT  = (u16*)(ws + 118*MB);
  u16*  W1T  = (u16*)(ws + 120*MB);     // [4096,1024] 8MB
  u16*  W2T  = (u16*)(ws + 128*MB);     // [1024,4096] 8MB

  dim3 tb(256);
  wt_kernel<<<dim3(1024/32, 1024/32), tb, 0, stream>>>(Wq, WqT, 1024, 1024);
  wt_kernel<<<dim3(1024/32, 1024/32), tb, 0, stream>>>(Wk, WkT, 1024, 1024);
  wt_kernel<<<dim3(1024/32, 1024/32), tb, 0, stream>>>(Wv, WvT, 1024, 1024);
  wt_kernel<<<dim3(1024/32, 1024/32), tb, 0, stream>>>(Wo, WoT, 1024, 1024);
  wt_kernel<<<dim3(4096/32, 1024/32), tb, 0, stream>>>(W1, W1T, 1024, 4096);
  wt_kernel<<<dim3(1024/32, 4096/32), tb, 0, stream>>>(W2, W2T, 4096, 1024);

  ln_kernel<<<ROWS, tb, 0, stream>>>(x, g1, be1, hln);

  dim3 gb(512);
  // fused QKV: one GEMM over [3072][1024] weights, routed epilogue (q pre-scaled)
  gemm256<3><<<dim3(3072/256, ROWS/128), gb, 0, stream>>>(hln, WqkvT, bq, nullptr, qb,
                                                          ROWS, 3072, 1024,
                                                          bk, bv, kb, vb);

  vtrans_kernel<<<dim3(SEQ/64, BATCH*NHEAD), tb, 0, stream>>>(vb, vt);

  attn_kernel<<<dim3(SEQ/128, BATCH*NHEAD), tb, 0, stream>>>(qb, kb, vt, mask, attn);

  gemm256<1><<<dim3(1024/256, ROWS/128), gb, 0, stream>>>(attn, WoT, bo, x, x2,
                                                          ROWS, 1024, 1024,
                                                          nullptr, nullptr, nullptr, nullptr);

  ln_kernel<<<ROWS, tb, 0, stream>>>(x2, g2, be2, hln);

  gemm256<2><<<dim3(4096/256, ROWS/128), gb, 0, stream>>>(hln, W1T, b1, nullptr, ff1,
                                                          ROWS, 4096, 1024,
                                                          nullptr, nullptr, nullptr, nullptr);

  gemm256<1><<<dim3(1024/256, ROWS/128), gb, 0, stream>>>(ff1, W2T, b2, x2, (float*)d_out,
                                                          ROWS, 1024, 4096,
                                                          nullptr, nullptr, nullptr, nullptr);
}